// Round 1
// baseline (4763.910 us; speedup 1.0000x reference)
//
#include <hip/hip_runtime.h>
#include <math.h>

#define NB 1024
#define DD 256
#define NTOK 64
#define NSLOT 8
#define NITER 5

__device__ __forceinline__ float sigmoidf_(float x) { return 1.f / (1.f + expf(-x)); }

__launch_bounds__(512)
__global__ void slot_attn_kernel(
    const float* __restrict__ g_in,      // [B,256,8,8]
    const float* __restrict__ g_noise,   // [B,8,256]
    const float* __restrict__ g_posW,    // [4,256]
    const float* __restrict__ g_posb,    // [256]
    const float* __restrict__ g_enw,     // [64,256]
    const float* __restrict__ g_enb,     // [64,256]
    const float* __restrict__ g_f1W, const float* __restrict__ g_f1b,
    const float* __restrict__ g_f2W, const float* __restrict__ g_f2b,
    const float* __restrict__ g_niw, const float* __restrict__ g_nib,
    const float* __restrict__ g_qW,  const float* __restrict__ g_qb,
    const float* __restrict__ g_kW,  const float* __restrict__ g_kb,
    const float* __restrict__ g_vW,  const float* __restrict__ g_vb,
    const float* __restrict__ g_gih, const float* __restrict__ g_ghh,
    const float* __restrict__ g_bih, const float* __restrict__ g_bhh,
    const float* __restrict__ g_nsw, const float* __restrict__ g_nsb,
    const float* __restrict__ g_pfw, const float* __restrict__ g_pfb,
    const float* __restrict__ g_m1W, const float* __restrict__ g_m1b,
    const float* __restrict__ g_m2W, const float* __restrict__ g_m2b,
    const float* __restrict__ g_mu,  const float* __restrict__ g_sig,
    float* __restrict__ g_out)
{
    // LDS: 65536 + 65792 + 24576 + 2048 + 64 = 158016 B  (<160 KiB, 1 block/CU)
    __shared__ float xs[NTOK][DD];        // encoder activations; later holds V
    __shared__ float ks[NTOK][DD + 1];    // K, +1 pad -> per-lane-row reads 2-way (free)
    __shared__ float sb[3][NSLOT][DD];    // slot ping-pong (2) + scratch (1)
    __shared__ float attn[NSLOT][NTOK];
    __shared__ float red[16];

    const int b    = blockIdx.x;
    const int t    = threadIdx.x;
    const int lane = t & 63;
    const int wave = t >> 6;

    // ---------------- stage 0: load + SoftPositionEmbed (transpose [D,HW]->[HW,D]) ---
    const float* inb = g_in + (size_t)b * (DD * NTOK);
    float psum = 0.f, psq = 0.f;
    for (int i = 0; i < 8; ++i) {
        int idx4 = i * 512 + t;          // float4 index into [256][64] input
        int d  = idx4 >> 4;
        int r0 = (idx4 & 15) << 2;
        float4 v = ((const float4*)inb)[idx4];
        float pw0 = g_posW[d], pw1 = g_posW[256 + d], pw2 = g_posW[512 + d], pw3 = g_posW[768 + d];
        float pb = g_posb[d];
        float vals[4] = {v.x, v.y, v.z, v.w};
        #pragma unroll
        for (int q = 0; q < 4; ++q) {
            int r = r0 + q;
            float fh = (float)(r >> 3) * (1.f / 7.f);
            float fw = (float)(r & 7) * (1.f / 7.f);
            float pos = fh * pw0 + fw * pw1 + (1.f - fh) * pw2 + (1.f - fw) * pw3 + pb;
            float x = vals[q] + pos;
            xs[r][d] = x;
            psum += x; psq += x * x;
        }
    }
    // ---------------- LN over ALL 64x256 (enln) ----------------
    #pragma unroll
    for (int m = 32; m >= 1; m >>= 1) { psum += __shfl_xor(psum, m); psq += __shfl_xor(psq, m); }
    if (lane == 0) { red[wave] = psum; red[8 + wave] = psq; }
    __syncthreads();
    {
        float tsum = 0.f, tsq = 0.f;
        #pragma unroll
        for (int w2 = 0; w2 < 8; ++w2) { tsum += red[w2]; tsq += red[8 + w2]; }
        float mu  = tsum * (1.f / 16384.f);
        float var = tsq * (1.f / 16384.f) - mu * mu;
        float rs  = rsqrtf(var + 1e-5f);
        for (int i = 0; i < 8; ++i) {
            int idx4 = t + 512 * i;
            float4 v  = ((float4*)xs)[idx4];
            float4 w4 = ((const float4*)g_enw)[idx4];
            float4 b4 = ((const float4*)g_enb)[idx4];
            v.x = (v.x - mu) * rs * w4.x + b4.x;
            v.y = (v.y - mu) * rs * w4.y + b4.y;
            v.z = (v.z - mu) * rs * w4.z + b4.z;
            v.w = (v.w - mu) * rs * w4.w + b4.w;
            ((float4*)xs)[idx4] = v;
        }
    }
    __syncthreads();

    // ---------------- encoder GEMMs: [64,256]@[256,256] ----------------
    // thread tile: 4 rows x 8 cols; rt=t>>5 (0..15), ct=t&31
    auto enc_gemm = [&](const float* __restrict__ W, const float* __restrict__ bias, int mode) {
        const int r0 = (t >> 5) << 2;
        const int c0 = (t & 31) << 3;
        float acc[4][8];
        #pragma unroll
        for (int i = 0; i < 4; ++i)
            #pragma unroll
            for (int j = 0; j < 8; ++j) acc[i][j] = 0.f;
        for (int kk = 0; kk < 256; kk += 4) {
            float4 xv[4];
            #pragma unroll
            for (int i = 0; i < 4; ++i) xv[i] = *(const float4*)&xs[r0 + i][kk];
            float4 wa[4], wb[4];
            #pragma unroll
            for (int q = 0; q < 4; ++q) {
                const float* wp = W + (size_t)(kk + q) * 256 + c0;
                wa[q] = *(const float4*)wp;
                wb[q] = *(const float4*)(wp + 4);
            }
            #pragma unroll
            for (int i = 0; i < 4; ++i) {
                float xq[4] = {xv[i].x, xv[i].y, xv[i].z, xv[i].w};
                #pragma unroll
                for (int q = 0; q < 4; ++q) {
                    acc[i][0] += xq[q] * wa[q].x;
                    acc[i][1] += xq[q] * wa[q].y;
                    acc[i][2] += xq[q] * wa[q].z;
                    acc[i][3] += xq[q] * wa[q].w;
                    acc[i][4] += xq[q] * wb[q].x;
                    acc[i][5] += xq[q] * wb[q].y;
                    acc[i][6] += xq[q] * wb[q].z;
                    acc[i][7] += xq[q] * wb[q].w;
                }
            }
        }
        float bb[8];
        #pragma unroll
        for (int j = 0; j < 8; ++j) bb[j] = bias[c0 + j];
        if (mode == 0) {                 // relu, in-place xs
            __syncthreads();
            #pragma unroll
            for (int i = 0; i < 4; ++i)
                #pragma unroll
                for (int j = 0; j < 8; ++j)
                    xs[r0 + i][c0 + j] = fmaxf(acc[i][j] + bb[j], 0.f);
            __syncthreads();
        } else if (mode == 1) {          // -> ks (separate buffer, no barrier needed)
            #pragma unroll
            for (int i = 0; i < 4; ++i)
                #pragma unroll
                for (int j = 0; j < 8; ++j)
                    ks[r0 + i][c0 + j] = acc[i][j] + bb[j];
        } else {                         // V -> xs (reg-staged, barrier both sides)
            __syncthreads();
            #pragma unroll
            for (int i = 0; i < 4; ++i)
                #pragma unroll
                for (int j = 0; j < 8; ++j)
                    xs[r0 + i][c0 + j] = acc[i][j] + bb[j];
            __syncthreads();
        }
    };

    enc_gemm(g_f1W, g_f1b, 0);
    enc_gemm(g_f2W, g_f2b, 0);

    // ---------------- per-token LN (ni) in-place ----------------
    for (int i = 0; i < 8; ++i) {
        int row = wave + 8 * i;
        float4 v = ((float4*)xs)[row * 64 + lane];
        float s1 = v.x + v.y + v.z + v.w;
        float s2 = v.x * v.x + v.y * v.y + v.z * v.z + v.w * v.w;
        #pragma unroll
        for (int m = 32; m >= 1; m >>= 1) { s1 += __shfl_xor(s1, m); s2 += __shfl_xor(s2, m); }
        float mu2 = s1 * (1.f / 256.f);
        float rs2 = rsqrtf(s2 * (1.f / 256.f) - mu2 * mu2 + 1e-5f);
        float4 w4 = ((const float4*)g_niw)[lane];
        float4 b4 = ((const float4*)g_nib)[lane];
        v.x = (v.x - mu2) * rs2 * w4.x + b4.x;
        v.y = (v.y - mu2) * rs2 * w4.y + b4.y;
        v.z = (v.z - mu2) * rs2 * w4.z + b4.z;
        v.w = (v.w - mu2) * rs2 * w4.w + b4.w;
        ((float4*)xs)[row * 64 + lane] = v;
    }
    __syncthreads();

    enc_gemm(g_kW, g_kb, 1);   // K -> ks
    enc_gemm(g_vW, g_vb, 2);   // V -> xs

    // ---------------- slot init ----------------
    for (int i = 0; i < 4; ++i) {
        int e = t + 512 * i;             // 0..2047
        int d = e & 255;
        ((float*)sb[0])[e] = g_mu[d] + expf(0.5f * g_sig[d]) * g_noise[(size_t)b * 2048 + e];
    }
    __syncthreads();

    // per-slot LN helper: wave w handles slot w
    auto ln8 = [&](float (*src)[DD], float (*dst)[DD],
                   const float* __restrict__ lw, const float* __restrict__ lb) {
        float4 v = ((const float4*)src[wave])[lane];
        float s1 = v.x + v.y + v.z + v.w;
        float s2 = v.x * v.x + v.y * v.y + v.z * v.z + v.w * v.w;
        #pragma unroll
        for (int m = 32; m >= 1; m >>= 1) { s1 += __shfl_xor(s1, m); s2 += __shfl_xor(s2, m); }
        float mu_ = s1 * (1.f / 256.f);
        float rs_ = rsqrtf(s2 * (1.f / 256.f) - mu_ * mu_ + 1e-5f);
        float4 w4 = ((const float4*)lw)[lane];
        float4 b4 = ((const float4*)lb)[lane];
        float4 o;
        o.x = (v.x - mu_) * rs_ * w4.x + b4.x;
        o.y = (v.y - mu_) * rs_ * w4.y + b4.y;
        o.z = (v.z - mu_) * rs_ * w4.z + b4.z;
        o.w = (v.w - mu_) * rs_ * w4.w + b4.w;
        ((float4*)dst[wave])[lane] = o;
    };

    // slot-side GEMM [8,256]@[256,256]: thread -> col c, 4 slots
    auto slot_gemm = [&](float (*A)[DD], const float* __restrict__ W,
                         const float* __restrict__ bias, float (*O)[DD], int mode) {
        const int c  = t & 255;
        const int sh = (t >> 8) << 2;
        float acc[4] = {0.f, 0.f, 0.f, 0.f};
        for (int k = 0; k < 256; k += 4) {
            float w0 = W[(size_t)(k + 0) * 256 + c];
            float w1 = W[(size_t)(k + 1) * 256 + c];
            float w2 = W[(size_t)(k + 2) * 256 + c];
            float w3 = W[(size_t)(k + 3) * 256 + c];
            #pragma unroll
            for (int s = 0; s < 4; ++s) {
                float4 a = *(const float4*)&A[sh + s][k];
                acc[s] += a.x * w0 + a.y * w1 + a.z * w2 + a.w * w3;
            }
        }
        #pragma unroll
        for (int s = 0; s < 4; ++s) {
            float r = acc[s] + bias[c];
            if (mode == 1) r = fmaxf(r, 0.f);
            if (mode == 2) O[sh + s][c] += r;
            else           O[sh + s][c]  = r;
        }
    };

    int p = 0;
    for (int it = 0; it < NITER; ++it) {
        float (*S)[DD] = sb[p];
        float (*Y)[DD] = sb[1 - p];
        float (*X)[DD] = sb[2];

        ln8(S, X, g_nsw, g_nsb);               // norm_slots -> X
        __syncthreads();
        slot_gemm(X, g_qW, g_qb, Y, 0);        // q -> Y
        __syncthreads();

        // dots[s][j] = scale * q[s] . k[j] : s=wave, j=lane
        {
            float acc = 0.f;
            const float* kr = ks[lane];
            const float* qr = Y[wave];
            for (int d0 = 0; d0 < 256; d0 += 4)
                acc += qr[d0] * kr[d0] + qr[d0 + 1] * kr[d0 + 1]
                     + qr[d0 + 2] * kr[d0 + 2] + qr[d0 + 3] * kr[d0 + 3];
            attn[wave][lane] = acc * 0.0625f;
        }
        __syncthreads();

        // softmax over SLOT axis per token column + EPS
        if (t < 64) {
            float mx = attn[0][t];
            #pragma unroll
            for (int s = 1; s < 8; ++s) mx = fmaxf(mx, attn[s][t]);
            float e[8], den = 0.f;
            #pragma unroll
            for (int s = 0; s < 8; ++s) { e[s] = expf(attn[s][t] - mx); den += e[s]; }
            float inv = 1.f / den;
            #pragma unroll
            for (int s = 0; s < 8; ++s) attn[s][t] = e[s] * inv + 1e-8f;
        }
        __syncthreads();

        // renormalize over tokens: slot = wave
        {
            float v = attn[wave][lane];
            float ssum = v;
            #pragma unroll
            for (int m = 32; m >= 1; m >>= 1) ssum += __shfl_xor(ssum, m);
            attn[wave][lane] = v / ssum;
        }
        __syncthreads();

        // updates = attn @ V -> X
        {
            const int c = t & 255, sh = (t >> 8) << 2;
            float acc[4] = {0.f, 0.f, 0.f, 0.f};
            for (int j = 0; j < 64; ++j) {
                float vv = xs[j][c];
                #pragma unroll
                for (int s = 0; s < 4; ++s) acc[s] += attn[sh + s][j] * vv;
            }
            #pragma unroll
            for (int s = 0; s < 4; ++s) X[sh + s][c] = acc[s];
        }
        __syncthreads();

        // GRUCell(updates=X, hidden=S) -> Y
        {
            const int c = t & 255, sh = (t >> 8) << 2;
            float axr[4] = {}, axz[4] = {}, axn[4] = {}, ahr[4] = {}, ahz[4] = {}, ahn[4] = {};
            const float* Wxr = g_gih + (size_t)c * 256;
            const float* Wxz = g_gih + (size_t)(c + 256) * 256;
            const float* Wxn = g_gih + (size_t)(c + 512) * 256;
            const float* Whr = g_ghh + (size_t)c * 256;
            const float* Whz = g_ghh + (size_t)(c + 256) * 256;
            const float* Whn = g_ghh + (size_t)(c + 512) * 256;
            for (int k = 0; k < 256; k += 4) {
                float4 wxr = *(const float4*)&Wxr[k];
                float4 wxz = *(const float4*)&Wxz[k];
                float4 wxn = *(const float4*)&Wxn[k];
                float4 whr = *(const float4*)&Whr[k];
                float4 whz = *(const float4*)&Whz[k];
                float4 whn = *(const float4*)&Whn[k];
                #pragma unroll
                for (int s = 0; s < 4; ++s) {
                    float4 U = *(const float4*)&X[sh + s][k];
                    float4 P = *(const float4*)&S[sh + s][k];
                    axr[s] += U.x * wxr.x + U.y * wxr.y + U.z * wxr.z + U.w * wxr.w;
                    axz[s] += U.x * wxz.x + U.y * wxz.y + U.z * wxz.z + U.w * wxz.w;
                    axn[s] += U.x * wxn.x + U.y * wxn.y + U.z * wxn.z + U.w * wxn.w;
                    ahr[s] += P.x * whr.x + P.y * whr.y + P.z * whr.z + P.w * whr.w;
                    ahz[s] += P.x * whz.x + P.y * whz.y + P.z * whz.z + P.w * whz.w;
                    ahn[s] += P.x * whn.x + P.y * whn.y + P.z * whn.z + P.w * whn.w;
                }
            }
            float bxr = g_bih[c], bxz = g_bih[c + 256], bxn = g_bih[c + 512];
            float bhr = g_bhh[c], bhz = g_bhh[c + 256], bhn = g_bhh[c + 512];
            #pragma unroll
            for (int s = 0; s < 4; ++s) {
                float rr = sigmoidf_(axr[s] + bxr + ahr[s] + bhr);
                float zz = sigmoidf_(axz[s] + bxz + ahz[s] + bhz);
                float nn = tanhf(axn[s] + bxn + rr * (ahn[s] + bhn));
                Y[sh + s][c] = (1.f - zz) * nn + zz * S[sh + s][c];
            }
        }
        __syncthreads();

        // residual MLP: h = relu(LN(Y)@m1W + m1b); Y += h@m2W + m2b
        ln8(Y, X, g_pfw, g_pfb);
        __syncthreads();
        slot_gemm(X, g_m1W, g_m1b, S, 1);      // h -> S (old slots dead)
        __syncthreads();
        slot_gemm(S, g_m2W, g_m2b, Y, 2);      // Y += mlp out
        __syncthreads();

        p ^= 1;
    }

    // ---------------- output ----------------
    float* ob = g_out + (size_t)b * 2048;
    const float* fin = (const float*)sb[p];
    for (int i = 0; i < 4; ++i) {
        int e = t + 512 * i;
        ob[e] = fin[e];
    }
}

extern "C" void kernel_launch(void* const* d_in, const int* in_sizes, int n_in,
                              void* d_out, int out_size, void* d_ws, size_t ws_size,
                              hipStream_t stream) {
    (void)in_sizes; (void)n_in; (void)d_ws; (void)ws_size; (void)out_size;
    slot_attn_kernel<<<dim3(NB), dim3(512), 0, stream>>>(
        (const float*)d_in[0],  (const float*)d_in[1],  (const float*)d_in[2],  (const float*)d_in[3],
        (const float*)d_in[4],  (const float*)d_in[5],  (const float*)d_in[6],  (const float*)d_in[7],
        (const float*)d_in[8],  (const float*)d_in[9],  (const float*)d_in[10], (const float*)d_in[11],
        (const float*)d_in[12], (const float*)d_in[13], (const float*)d_in[14], (const float*)d_in[15],
        (const float*)d_in[16], (const float*)d_in[17], (const float*)d_in[18], (const float*)d_in[19],
        (const float*)d_in[20], (const float*)d_in[21], (const float*)d_in[22], (const float*)d_in[23],
        (const float*)d_in[24], (const float*)d_in[25], (const float*)d_in[26], (const float*)d_in[27],
        (const float*)d_in[28], (const float*)d_in[29], (const float*)d_in[30], (const float*)d_in[31],
        (float*)d_out);
}

// Round 2
// 1588.628 us; speedup vs baseline: 2.9988x; 2.9988x over previous
//
#include <hip/hip_runtime.h>
#include <math.h>

#define NB 1024
#define DD 256
#define NTOK 64
#define NSLOT 8
#define NITER 5

typedef __attribute__((ext_vector_type(8))) short short8;
typedef __attribute__((ext_vector_type(4))) float f32x4;
typedef unsigned long long ull;

__device__ __forceinline__ unsigned short f2bf(float f) {
    union { float f; unsigned u; } x; x.f = f;
    unsigned r = x.u + 0x7fffu + ((x.u >> 16) & 1u);
    return (unsigned short)(r >> 16);
}
__device__ __forceinline__ float bf2f(unsigned short h) {
    union { unsigned u; float f; } x; x.u = ((unsigned)h) << 16;
    return x.f;
}
__device__ __forceinline__ float sigmoidf_(float x) { return 1.f / (1.f + expf(-x)); }

// ---------------- weight preconvert: f32 -> bf16, [k][n] -> [n][k] ----------------
// ws layout (u16 elems): f1t:0 f2t:65536 kt:131072 vt:196608 qt:262144 m1t:327680
//                        m2t:393216 gihb:458752 ghhb:655360   (total 851968 = 1.7MB)
__global__ void convert_weights(
    const float* __restrict__ f1W, const float* __restrict__ f2W,
    const float* __restrict__ kW,  const float* __restrict__ vW,
    const float* __restrict__ qW,  const float* __restrict__ m1W,
    const float* __restrict__ m2W, const float* __restrict__ gih,
    const float* __restrict__ ghh, unsigned short* __restrict__ out)
{
    int id = blockIdx.x * 512 + threadIdx.x;
    if (id < 7 * 65536) {                       // transpose [k][n] -> [n][k]
        int mi = id >> 16, e = id & 65535;
        int k = e >> 8, n = e & 255;
        const float* src = mi == 0 ? f1W : mi == 1 ? f2W : mi == 2 ? kW :
                           mi == 3 ? vW  : mi == 4 ? qW  : mi == 5 ? m1W : m2W;
        out[mi * 65536 + n * 256 + k] = f2bf(src[e]);      // src[e]=src[k*256+n]
    } else if (id < 851968) {                   // gih/ghh are already [n][k]
        int e = id - 7 * 65536;
        const float* src = e < 196608 ? gih : ghh;
        int ee = e < 196608 ? e : e - 196608;
        out[458752 + e] = f2bf(src[ee]);
    }
}

// swizzled bf16 LDS helpers (row-major, 256 or 64 cols; XOR bits 3..5 of u16 idx)
__device__ __forceinline__ short8 afrag256(const unsigned short* buf, int row, int k) {
    return *(const short8*)(buf + row * 256 + (k ^ ((row & 7) << 3)));
}
__device__ __forceinline__ short8 afrag64(const unsigned short* buf, int row, int k) {
    return *(const short8*)(buf + row * 64 + (k ^ ((row & 7) << 3)));
}
__device__ __forceinline__ void st256(unsigned short* buf, int row, int col, float v) {
    buf[row * 256 + (col ^ ((row & 7) << 3))] = f2bf(v);
}

__launch_bounds__(512)
__global__ void slot_attn_kernel(
    const float* __restrict__ g_in, const float* __restrict__ g_noise,
    const float* __restrict__ g_posW, const float* __restrict__ g_posb,
    const float* __restrict__ g_enw, const float* __restrict__ g_enb,
    const float* __restrict__ g_f1b, const float* __restrict__ g_f2b,
    const float* __restrict__ g_niw, const float* __restrict__ g_nib,
    const float* __restrict__ g_qb,  const float* __restrict__ g_kb,
    const float* __restrict__ g_vb,
    const float* __restrict__ g_bih, const float* __restrict__ g_bhh,
    const float* __restrict__ g_nsw, const float* __restrict__ g_nsb,
    const float* __restrict__ g_pfw, const float* __restrict__ g_pfb,
    const float* __restrict__ g_m1b, const float* __restrict__ g_m2b,
    const float* __restrict__ g_mu,  const float* __restrict__ g_sig,
    const unsigned short* __restrict__ wsb,
    float* __restrict__ g_out)
{
    __shared__ unsigned short xs[64 * 256];     // encoder activations (bf16, swz)
    __shared__ unsigned short ks[64 * 256];     // K  [token][dim]
    __shared__ unsigned short vt[256 * 64];     // V^T [dim][token]
    __shared__ unsigned short abLN[16 * 256];   // LN outputs (A-operand)
    __shared__ unsigned short abT[16 * 256];    // q / updates / mlp-h (A-operand)
    __shared__ unsigned short abS[16 * 256];    // raw slots (A-operand for GRU hh)
    __shared__ unsigned short attn_bf[16 * 64]; // attn (A-operand for updates)
    __shared__ float sbf[2][NSLOT][DD];         // slots f32 ping-pong
    __shared__ float attn_f[NSLOT][72];
    __shared__ float red[16];

    const int b    = blockIdx.x;
    const int t    = threadIdx.x;
    const int lane = t & 63;
    const int wave = t >> 6;
    const int lr   = lane & 15;
    const int lk   = (lane >> 4) * 8;
    const int mr   = (lane >> 4) * 4;           // C-frag base row

    const unsigned short* f1t  = wsb;
    const unsigned short* f2t  = wsb + 65536;
    const unsigned short* kt   = wsb + 131072;
    const unsigned short* vwt  = wsb + 196608;
    const unsigned short* qt   = wsb + 262144;
    const unsigned short* m1t  = wsb + 327680;
    const unsigned short* m2t  = wsb + 393216;
    const unsigned short* gihb = wsb + 458752;
    const unsigned short* ghhb = wsb + 655360;

    // zero A-buffers (pad rows must be 0)
    for (int i = t; i < 4096; i += 512) { abLN[i] = 0; abT[i] = 0; abS[i] = 0; }
    for (int i = t; i < 1024; i += 512) attn_bf[i] = 0;

    // ---------- stage 0: load + SoftPositionEmbed, transpose to [tok][dim] bf16 ----
    const float* inb = g_in + (size_t)b * (DD * NTOK);
    float psum = 0.f, psq = 0.f;
    for (int i = 0; i < 8; ++i) {
        int idx4 = i * 512 + t;
        int d  = idx4 >> 4;
        int r0 = (idx4 & 15) << 2;
        float4 v = ((const float4*)inb)[idx4];
        float pw0 = g_posW[d], pw1 = g_posW[256 + d], pw2 = g_posW[512 + d], pw3 = g_posW[768 + d];
        float pb = g_posb[d];
        float vals[4] = {v.x, v.y, v.z, v.w};
        #pragma unroll
        for (int q = 0; q < 4; ++q) {
            int r = r0 + q;
            float fh = (float)(r >> 3) * (1.f / 7.f);
            float fw = (float)(r & 7) * (1.f / 7.f);
            float x = vals[q] + fh * pw0 + fw * pw1 + (1.f - fh) * pw2 + (1.f - fw) * pw3 + pb;
            st256(xs, r, d, x);
            psum += x; psq += x * x;
        }
    }
    #pragma unroll
    for (int m = 32; m >= 1; m >>= 1) { psum += __shfl_xor(psum, m); psq += __shfl_xor(psq, m); }
    if (lane == 0) { red[wave] = psum; red[8 + wave] = psq; }
    __syncthreads();
    // ---------- enln over all 64x256 ----------
    {
        float tsum = 0.f, tsq = 0.f;
        #pragma unroll
        for (int w2 = 0; w2 < 8; ++w2) { tsum += red[w2]; tsq += red[8 + w2]; }
        float mu  = tsum * (1.f / 16384.f);
        float rs  = rsqrtf(tsq * (1.f / 16384.f) - mu * mu + 1e-5f);
        int row = t >> 3, c0 = (t & 7) * 32;
        for (int j = 0; j < 8; ++j) {
            int c = c0 + j * 4;
            ull* p = (ull*)(xs + row * 256 + (c ^ ((row & 7) << 3)));
            ull pk = *p;
            float4 w4 = *(const float4*)&g_enw[row * 256 + c];
            float4 b4 = *(const float4*)&g_enb[row * 256 + c];
            float v0 = (bf2f((unsigned short)pk)         - mu) * rs * w4.x + b4.x;
            float v1 = (bf2f((unsigned short)(pk >> 16)) - mu) * rs * w4.y + b4.y;
            float v2 = (bf2f((unsigned short)(pk >> 32)) - mu) * rs * w4.z + b4.z;
            float v3 = (bf2f((unsigned short)(pk >> 48)) - mu) * rs * w4.w + b4.w;
            *p = (ull)f2bf(v0) | ((ull)f2bf(v1) << 16) | ((ull)f2bf(v2) << 32) | ((ull)f2bf(v3) << 48);
        }
    }
    __syncthreads();

    // ---------- encoder GEMM: xs[64,256] @ Wt -> (mode 0: relu->xs, 1: ->ks, 2: ->vt^T)
    auto enc_gemm = [&](const unsigned short* Wt, const float* __restrict__ bias, int mode) {
        const int m0 = (wave & 3) * 16;
        const int nb = (wave >> 2) * 128;
        short8 af[8];
        #pragma unroll
        for (int kk = 0; kk < 8; ++kk) af[kk] = afrag256(xs, m0 + lr, kk * 32 + lk);
        f32x4 acc[8];
        #pragma unroll
        for (int f = 0; f < 8; ++f) {
            acc[f] = (f32x4){0.f, 0.f, 0.f, 0.f};
            const unsigned short* wp = Wt + (size_t)(nb + f * 16 + lr) * 256 + lk;
            #pragma unroll
            for (int kk = 0; kk < 8; ++kk)
                acc[f] = __builtin_amdgcn_mfma_f32_16x16x32_bf16(af[kk], *(const short8*)(wp + kk * 32), acc[f], 0, 0, 0);
        }
        __syncthreads();
        #pragma unroll
        for (int f = 0; f < 8; ++f) {
            int col = nb + f * 16 + lr;
            float bv = bias[col];
            if (mode == 2) {                      // V^T: pack 4 consecutive tokens
                int t0 = m0 + mr;
                ull pk = (ull)f2bf(acc[f][0] + bv) | ((ull)f2bf(acc[f][1] + bv) << 16)
                       | ((ull)f2bf(acc[f][2] + bv) << 32) | ((ull)f2bf(acc[f][3] + bv) << 48);
                *(ull*)(vt + col * 64 + (t0 ^ ((col & 7) << 3))) = pk;
            } else {
                #pragma unroll
                for (int r = 0; r < 4; ++r) {
                    float v = acc[f][r] + bv;
                    if (mode == 0) st256(xs, m0 + mr + r, col, fmaxf(v, 0.f));
                    else           st256(ks, m0 + mr + r, col, v);
                }
            }
        }
        __syncthreads();
    };

    enc_gemm(f1t, g_f1b, 0);
    enc_gemm(f2t, g_f2b, 0);

    // ---------- per-token LN (ni), in place on xs ----------
    for (int i = 0; i < 8; ++i) {
        int row = wave * 8 + i;
        ull* p = (ull*)(xs + row * 256 + ((lane * 4) ^ ((row & 7) << 3)));
        ull pk = *p;
        float v0 = bf2f((unsigned short)pk),        v1 = bf2f((unsigned short)(pk >> 16));
        float v2 = bf2f((unsigned short)(pk >> 32)), v3 = bf2f((unsigned short)(pk >> 48));
        float s1 = v0 + v1 + v2 + v3;
        float s2 = v0 * v0 + v1 * v1 + v2 * v2 + v3 * v3;
        #pragma unroll
        for (int m = 32; m >= 1; m >>= 1) { s1 += __shfl_xor(s1, m); s2 += __shfl_xor(s2, m); }
        float mu2 = s1 * (1.f / 256.f);
        float rs2 = rsqrtf(s2 * (1.f / 256.f) - mu2 * mu2 + 1e-5f);
        float4 w4 = *(const float4*)&g_niw[lane * 4];
        float4 b4 = *(const float4*)&g_nib[lane * 4];
        v0 = (v0 - mu2) * rs2 * w4.x + b4.x;
        v1 = (v1 - mu2) * rs2 * w4.y + b4.y;
        v2 = (v2 - mu2) * rs2 * w4.z + b4.z;
        v3 = (v3 - mu2) * rs2 * w4.w + b4.w;
        *p = (ull)f2bf(v0) | ((ull)f2bf(v1) << 16) | ((ull)f2bf(v2) << 32) | ((ull)f2bf(v3) << 48);
    }
    __syncthreads();

    enc_gemm(kt,  g_kb, 1);      // K  -> ks
    enc_gemm(vwt, g_vb, 2);      // V  -> vt (transposed)

    // ---------- slot init ----------
    for (int i = 0; i < 4; ++i) {
        int e = t + 512 * i;
        int m = e >> 8, col = e & 255;
        float v = g_mu[col] + expf(0.5f * g_sig[col]) * g_noise[(size_t)b * 2048 + e];
        sbf[0][m][col] = v;
        st256(abS, m, col, v);
    }
    __syncthreads();

    // LN over one slot row (f32 src) -> abLN bf16
    auto ln_slots = [&](float (*src)[DD], const float* __restrict__ lw, const float* __restrict__ lb) {
        float4 v = ((const float4*)src[wave])[lane];
        float s1 = v.x + v.y + v.z + v.w;
        float s2 = v.x * v.x + v.y * v.y + v.z * v.z + v.w * v.w;
        #pragma unroll
        for (int m = 32; m >= 1; m >>= 1) { s1 += __shfl_xor(s1, m); s2 += __shfl_xor(s2, m); }
        float mu_ = s1 * (1.f / 256.f);
        float rs_ = rsqrtf(s2 * (1.f / 256.f) - mu_ * mu_ + 1e-5f);
        float4 w4 = *(const float4*)&lw[lane * 4];
        float4 b4 = *(const float4*)&lb[lane * 4];
        float o0 = (v.x - mu_) * rs_ * w4.x + b4.x;
        float o1 = (v.y - mu_) * rs_ * w4.y + b4.y;
        float o2 = (v.z - mu_) * rs_ * w4.z + b4.z;
        float o3 = (v.w - mu_) * rs_ * w4.w + b4.w;
        *(ull*)(abLN + wave * 256 + ((lane * 4) ^ ((wave & 7) << 3))) =
            (ull)f2bf(o0) | ((ull)f2bf(o1) << 16) | ((ull)f2bf(o2) << 32) | ((ull)f2bf(o3) << 48);
    };

    // [16,256]@[256,256] -> abT (+bias, opt relu); wave covers 32 cols
    auto sgemm_abT = [&](const unsigned short* A, const unsigned short* Wt,
                         const float* __restrict__ bias, bool relu) {
        short8 af[8];
        #pragma unroll
        for (int kk = 0; kk < 8; ++kk) af[kk] = afrag256(A, lr, kk * 32 + lk);
        #pragma unroll
        for (int c = 0; c < 2; ++c) {
            int col = wave * 32 + c * 16 + lr;
            f32x4 acc = (f32x4){0.f, 0.f, 0.f, 0.f};
            const unsigned short* wp = Wt + (size_t)col * 256 + lk;
            #pragma unroll
            for (int kk = 0; kk < 8; ++kk)
                acc = __builtin_amdgcn_mfma_f32_16x16x32_bf16(af[kk], *(const short8*)(wp + kk * 32), acc, 0, 0, 0);
            float bv = bias[col];
            #pragma unroll
            for (int r = 0; r < 4; ++r) {
                float v = acc[r] + bv;
                if (relu) v = fmaxf(v, 0.f);
                st256(abT, mr + r, col, v);
            }
        }
    };

    int p = 0;
    for (int it = 0; it < NITER; ++it) {
        float (*Sf)[DD] = sbf[p];
        float (*Yf)[DD] = sbf[p ^ 1];

        ln_slots(Sf, g_nsw, g_nsb);             // -> abLN
        __syncthreads();
        sgemm_abT(abLN, qt, g_qb, false);       // q -> abT
        __syncthreads();

        // dots = q @ K^T * scale   (waves 0-3, one 16-token frag each)
        if (wave < 4) {
            int n0 = wave * 16;
            f32x4 acc = (f32x4){0.f, 0.f, 0.f, 0.f};
            #pragma unroll
            for (int kk = 0; kk < 8; ++kk) {
                short8 a = afrag256(abT, lr, kk * 32 + lk);
                short8 kb = afrag256(ks, n0 + lr, kk * 32 + lk);
                acc = __builtin_amdgcn_mfma_f32_16x16x32_bf16(a, kb, acc, 0, 0, 0);
            }
            #pragma unroll
            for (int r = 0; r < 4; ++r)
                if (mr + r < 8) attn_f[mr + r][n0 + lr] = acc[r] * 0.0625f;
        }
        __syncthreads();

        // softmax over SLOT axis per token, + eps
        if (t < 64) {
            float mx = attn_f[0][t];
            #pragma unroll
            for (int s = 1; s < 8; ++s) mx = fmaxf(mx, attn_f[s][t]);
            float e[8], den = 0.f;
            #pragma unroll
            for (int s = 0; s < 8; ++s) { e[s] = expf(attn_f[s][t] - mx); den += e[s]; }
            float inv = 1.f / den;
            #pragma unroll
            for (int s = 0; s < 8; ++s) attn_f[s][t] = e[s] * inv + 1e-8f;
        }
        __syncthreads();

        // renormalize over tokens; write attn bf16 (slot=wave, tok=lane)
        {
            float v = attn_f[wave][lane];
            float ssum = v;
            #pragma unroll
            for (int m = 32; m >= 1; m >>= 1) ssum += __shfl_xor(ssum, m);
            attn_bf[wave * 64 + (lane ^ ((wave & 7) << 3))] = f2bf(v / ssum);
        }
        __syncthreads();

        // updates = attn @ V -> abT
        {
            short8 a0 = afrag64(attn_bf, lr, lk);
            short8 a1 = afrag64(attn_bf, lr, 32 + lk);
            #pragma unroll
            for (int c = 0; c < 2; ++c) {
                int col = wave * 32 + c * 16 + lr;
                f32x4 acc = (f32x4){0.f, 0.f, 0.f, 0.f};
                acc = __builtin_amdgcn_mfma_f32_16x16x32_bf16(a0, afrag64(vt, col, lk), acc, 0, 0, 0);
                acc = __builtin_amdgcn_mfma_f32_16x16x32_bf16(a1, afrag64(vt, col, 32 + lk), acc, 0, 0, 0);
                #pragma unroll
                for (int r = 0; r < 4; ++r) st256(abT, mr + r, col, acc[r]);
            }
        }
        __syncthreads();

        // GRU: gx = U@gih^T + bih, gh = S@ghh^T + bhh (wave covers 32 output dims x 3 gates)
        {
            short8 uf[8], sf[8];
            #pragma unroll
            for (int kk = 0; kk < 8; ++kk) {
                uf[kk] = afrag256(abT, lr, kk * 32 + lk);
                sf[kk] = afrag256(abS, lr, kk * 32 + lk);
            }
            f32x4 ax[3][2], ah[3][2];
            #pragma unroll
            for (int g = 0; g < 3; ++g)
            #pragma unroll
            for (int c = 0; c < 2; ++c) {
                ax[g][c] = (f32x4){0.f, 0.f, 0.f, 0.f};
                ah[g][c] = (f32x4){0.f, 0.f, 0.f, 0.f};
                int n = g * 256 + wave * 32 + c * 16 + lr;
                const unsigned short* bx = gihb + (size_t)n * 256 + lk;
                const unsigned short* bh = ghhb + (size_t)n * 256 + lk;
                #pragma unroll
                for (int kk = 0; kk < 8; ++kk) {
                    ax[g][c] = __builtin_amdgcn_mfma_f32_16x16x32_bf16(uf[kk], *(const short8*)(bx + kk * 32), ax[g][c], 0, 0, 0);
                    ah[g][c] = __builtin_amdgcn_mfma_f32_16x16x32_bf16(sf[kk], *(const short8*)(bh + kk * 32), ah[g][c], 0, 0, 0);
                }
            }
            #pragma unroll
            for (int c = 0; c < 2; ++c) {
                int col = wave * 32 + c * 16 + lr;
                float bxr = g_bih[col], bxz = g_bih[col + 256], bxn = g_bih[col + 512];
                float bhr = g_bhh[col], bhz = g_bhh[col + 256], bhn = g_bhh[col + 512];
                #pragma unroll
                for (int r = 0; r < 4; ++r) {
                    int m = mr + r;
                    if (m < 8) {
                        float rr = sigmoidf_(ax[0][c][r] + bxr + ah[0][c][r] + bhr);
                        float zz = sigmoidf_(ax[1][c][r] + bxz + ah[1][c][r] + bhz);
                        float nn = tanhf(ax[2][c][r] + bxn + rr * (ah[2][c][r] + bhn));
                        Yf[m][col] = (1.f - zz) * nn + zz * Sf[m][col];
                    }
                }
            }
        }
        __syncthreads();

        ln_slots(Yf, g_pfw, g_pfb);             // -> abLN
        __syncthreads();
        sgemm_abT(abLN, m1t, g_m1b, true);      // h -> abT
        __syncthreads();

        // m2: slots = Yf + h @ m2W + m2b ; also refresh abS (bf16 raw slots)
        {
            short8 af[8];
            #pragma unroll
            for (int kk = 0; kk < 8; ++kk) af[kk] = afrag256(abT, lr, kk * 32 + lk);
            #pragma unroll
            for (int c = 0; c < 2; ++c) {
                int col = wave * 32 + c * 16 + lr;
                f32x4 acc = (f32x4){0.f, 0.f, 0.f, 0.f};
                const unsigned short* wp = m2t + (size_t)col * 256 + lk;
                #pragma unroll
                for (int kk = 0; kk < 8; ++kk)
                    acc = __builtin_amdgcn_mfma_f32_16x16x32_bf16(af[kk], *(const short8*)(wp + kk * 32), acc, 0, 0, 0);
                float bv = g_m2b[col];
                #pragma unroll
                for (int r = 0; r < 4; ++r) {
                    int m = mr + r;
                    if (m < 8) {
                        float v = acc[r] + bv + Yf[m][col];
                        Yf[m][col] = v;
                        st256(abS, m, col, v);
                    }
                }
            }
        }
        __syncthreads();

        p ^= 1;
    }

    float* ob = g_out + (size_t)b * 2048;
    for (int i = 0; i < 4; ++i) {
        int e = t + 512 * i;
        ob[e] = sbf[p][e >> 8][e & 255];
    }
}

extern "C" void kernel_launch(void* const* d_in, const int* in_sizes, int n_in,
                              void* d_out, int out_size, void* d_ws, size_t ws_size,
                              hipStream_t stream) {
    (void)in_sizes; (void)n_in; (void)ws_size; (void)out_size;
    unsigned short* wsb = (unsigned short*)d_ws;
    convert_weights<<<dim3(1664), dim3(512), 0, stream>>>(
        (const float*)d_in[6],  (const float*)d_in[8],   // f1W, f2W
        (const float*)d_in[14], (const float*)d_in[16],  // kW, vW
        (const float*)d_in[12], (const float*)d_in[26],  // qW, m1W
        (const float*)d_in[28],                          // m2W
        (const float*)d_in[18], (const float*)d_in[19],  // gih, ghh
        wsb);
    slot_attn_kernel<<<dim3(NB), dim3(512), 0, stream>>>(
        (const float*)d_in[0],  (const float*)d_in[1],   // inputs, noise
        (const float*)d_in[2],  (const float*)d_in[3],   // posW, posb
        (const float*)d_in[4],  (const float*)d_in[5],   // enln_w, enln_b
        (const float*)d_in[7],  (const float*)d_in[9],   // f1b, f2b
        (const float*)d_in[10], (const float*)d_in[11],  // ni_w, ni_b
        (const float*)d_in[13], (const float*)d_in[15],  // qb, kb
        (const float*)d_in[17],                          // vb
        (const float*)d_in[20], (const float*)d_in[21],  // bih, bhh
        (const float*)d_in[22], (const float*)d_in[23],  // ns_w, ns_b
        (const float*)d_in[24], (const float*)d_in[25],  // pf_w, pf_b
        (const float*)d_in[27], (const float*)d_in[29],  // m1b, m2b
        (const float*)d_in[30], (const float*)d_in[31],  // slots_mu, slots_sigma
        wsb,
        (float*)d_out);
}

// Round 3
// 937.800 us; speedup vs baseline: 5.0799x; 1.6940x over previous
//
#include <hip/hip_runtime.h>
#include <math.h>

// ------------------------------------------------------------------
// Multi-kernel GEMM-centric slot attention.  B=1024, D=256, tok=64,
// slots=8, iters=5.  ws (u16 units): W:0  bufA:1<<20  bufB:+16M  bufC:+32M
// ping/pong f32 after bufC.  Total ~114MB.
// ------------------------------------------------------------------

typedef __attribute__((ext_vector_type(8))) short short8;
typedef __attribute__((ext_vector_type(4))) float f32x4;
typedef unsigned long long ull;

__device__ __forceinline__ unsigned short f2bf(float f) {
    union { float f; unsigned u; } x; x.f = f;
    unsigned r = x.u + 0x7fffu + ((x.u >> 16) & 1u);
    return (unsigned short)(r >> 16);
}
__device__ __forceinline__ float bf2f(unsigned short h) {
    union { unsigned u; float f; } x; x.u = ((unsigned)h) << 16;
    return x.f;
}
__device__ __forceinline__ float sigmoidf_(float x) { return 1.f / (1.f + expf(-x)); }

__device__ __forceinline__ short8 afrag256(const unsigned short* buf, int row, int k) {
    return *(const short8*)(buf + row * 256 + (k ^ ((row & 7) << 3)));
}
__device__ __forceinline__ short8 afrag64(const unsigned short* buf, int row, int k) {
    return *(const short8*)(buf + row * 64 + (k ^ ((row & 7) << 3)));
}

__global__ void convert_weights(
    const float* __restrict__ f1W, const float* __restrict__ f2W,
    const float* __restrict__ kW,  const float* __restrict__ vW,
    const float* __restrict__ qW,  const float* __restrict__ m1W,
    const float* __restrict__ m2W, const float* __restrict__ gih,
    const float* __restrict__ ghh, unsigned short* __restrict__ out)
{
    int id = blockIdx.x * 512 + threadIdx.x;
    if (id < 7 * 65536) {
        int mi = id >> 16, e = id & 65535;
        int k = e >> 8, n = e & 255;
        const float* src = mi == 0 ? f1W : mi == 1 ? f2W : mi == 2 ? kW :
                           mi == 3 ? vW  : mi == 4 ? qW  : mi == 5 ? m1W : m2W;
        out[mi * 65536 + n * 256 + k] = f2bf(src[e]);
    } else if (id < 851968) {
        int e = id - 7 * 65536;
        const float* src = e < 196608 ? gih : ghh;
        int ee = e < 196608 ? e : e - 196608;
        out[458752 + e] = f2bf(src[ee]);
    }
}

__global__ void slot_init(const float* __restrict__ mu, const float* __restrict__ sig,
                          const float* __restrict__ noise, float* __restrict__ ping)
{
    int e = blockIdx.x * 512 + threadIdx.x;
    int col = e & 255;
    ping[e] = mu[col] + expf(0.5f * sig[col]) * noise[e];
}

__launch_bounds__(512)
__global__ void pos_ln_kernel(const float* __restrict__ g_in,
                              const float* __restrict__ g_posW, const float* __restrict__ g_posb,
                              const float* __restrict__ g_enw,  const float* __restrict__ g_enb,
                              unsigned short* __restrict__ outA)
{
    __shared__ unsigned short xs[64 * 256];
    __shared__ float red[16];
    const int b = blockIdx.x, t = threadIdx.x, lane = t & 63, wave = t >> 6;

    const float* inb = g_in + (size_t)b * 16384;
    float psum = 0.f, psq = 0.f;
    for (int i = 0; i < 8; ++i) {
        int idx4 = i * 512 + t;
        int d = idx4 >> 4;
        int r0 = (idx4 & 15) << 2;
        float4 v = ((const float4*)inb)[idx4];
        float pw0 = g_posW[d], pw1 = g_posW[256 + d], pw2 = g_posW[512 + d], pw3 = g_posW[768 + d];
        float pb = g_posb[d];
        float vals[4] = {v.x, v.y, v.z, v.w};
        #pragma unroll
        for (int q = 0; q < 4; ++q) {
            int r = r0 + q;
            float fh = (float)(r >> 3) * (1.f / 7.f);
            float fw = (float)(r & 7) * (1.f / 7.f);
            float x = vals[q] + fh * pw0 + fw * pw1 + (1.f - fh) * pw2 + (1.f - fw) * pw3 + pb;
            xs[r * 256 + (d ^ ((r & 7) << 3))] = f2bf(x);
            psum += x; psq += x * x;
        }
    }
    #pragma unroll
    for (int m = 32; m >= 1; m >>= 1) { psum += __shfl_xor(psum, m); psq += __shfl_xor(psq, m); }
    if (lane == 0) { red[wave] = psum; red[8 + wave] = psq; }
    __syncthreads();
    {
        float tsum = 0.f, tsq = 0.f;
        #pragma unroll
        for (int w2 = 0; w2 < 8; ++w2) { tsum += red[w2]; tsq += red[8 + w2]; }
        float mu = tsum * (1.f / 16384.f);
        float rs = rsqrtf(tsq * (1.f / 16384.f) - mu * mu + 1e-5f);
        int row = t >> 3, c0 = (t & 7) * 32;
        for (int j = 0; j < 8; ++j) {
            int c = c0 + j * 4;
            ull* p = (ull*)(xs + row * 256 + (c ^ ((row & 7) << 3)));
            ull pk = *p;
            float4 w4 = *(const float4*)&g_enw[row * 256 + c];
            float4 b4 = *(const float4*)&g_enb[row * 256 + c];
            float v0 = (bf2f((unsigned short)pk)         - mu) * rs * w4.x + b4.x;
            float v1 = (bf2f((unsigned short)(pk >> 16)) - mu) * rs * w4.y + b4.y;
            float v2 = (bf2f((unsigned short)(pk >> 32)) - mu) * rs * w4.z + b4.z;
            float v3 = (bf2f((unsigned short)(pk >> 48)) - mu) * rs * w4.w + b4.w;
            *p = (ull)f2bf(v0) | ((ull)f2bf(v1) << 16) | ((ull)f2bf(v2) << 32) | ((ull)f2bf(v3) << 48);
        }
    }
    __syncthreads();
    for (int i = 0; i < 8; ++i) {
        int s = t + 512 * i;
        int row = s >> 6, c4 = (s & 63) * 4;
        ull pk = *(const ull*)(xs + row * 256 + (c4 ^ ((row & 7) << 3)));
        *(ull*)(outA + (size_t)b * 16384 + row * 256 + c4) = pk;
    }
}

#define MODE_PLAIN 0
#define MODE_RELU  1
#define MODE_VT    2
#define MODE_RES   3

template<int MODE, int LNQ, int AF32>
__launch_bounds__(512)
__global__ void gemm64_kernel(const void* __restrict__ Ap,
                              const unsigned short* __restrict__ Wt,
                              const float* __restrict__ bias,
                              const float* __restrict__ lnw, const float* __restrict__ lnb,
                              void* __restrict__ Outp,
                              const float* __restrict__ Res)
{
    __shared__ unsigned short As[64 * 256];
    const int t = threadIdx.x, lane = t & 63, wave = t >> 6;
    const int m0 = blockIdx.x * 64;

    if (LNQ) {
        for (int r = 0; r < 8; ++r) {
            int row = wave * 8 + r;
            float v0, v1, v2, v3;
            if (AF32) {
                float4 v = *(const float4*)((const float*)Ap + (size_t)(m0 + row) * 256 + lane * 4);
                v0 = v.x; v1 = v.y; v2 = v.z; v3 = v.w;
            } else {
                ull pk = *(const ull*)((const unsigned short*)Ap + (size_t)(m0 + row) * 256 + lane * 4);
                v0 = bf2f((unsigned short)pk);         v1 = bf2f((unsigned short)(pk >> 16));
                v2 = bf2f((unsigned short)(pk >> 32)); v3 = bf2f((unsigned short)(pk >> 48));
            }
            float s1 = v0 + v1 + v2 + v3;
            float s2 = v0 * v0 + v1 * v1 + v2 * v2 + v3 * v3;
            #pragma unroll
            for (int m = 32; m >= 1; m >>= 1) { s1 += __shfl_xor(s1, m); s2 += __shfl_xor(s2, m); }
            float mu = s1 * (1.f / 256.f);
            float rs = rsqrtf(s2 * (1.f / 256.f) - mu * mu + 1e-5f);
            float4 w4 = *(const float4*)&lnw[lane * 4];
            float4 b4 = *(const float4*)&lnb[lane * 4];
            v0 = (v0 - mu) * rs * w4.x + b4.x;
            v1 = (v1 - mu) * rs * w4.y + b4.y;
            v2 = (v2 - mu) * rs * w4.z + b4.z;
            v3 = (v3 - mu) * rs * w4.w + b4.w;
            *(ull*)(As + row * 256 + ((lane * 4) ^ ((row & 7) << 3))) =
                (ull)f2bf(v0) | ((ull)f2bf(v1) << 16) | ((ull)f2bf(v2) << 32) | ((ull)f2bf(v3) << 48);
        }
    } else {
        for (int i = 0; i < 8; ++i) {
            int s = t + 512 * i;
            int row = s >> 6, c4 = (s & 63) * 4;
            ull pk = *(const ull*)((const unsigned short*)Ap + (size_t)(m0 + row) * 256 + c4);
            *(ull*)(As + row * 256 + (c4 ^ ((row & 7) << 3))) = pk;
        }
    }
    __syncthreads();

    const int lr = lane & 15, lk = (lane >> 4) * 8, mr = (lane >> 4) * 4;
    const int mi = wave & 3, nh = wave >> 2;

    short8 af[8];
    #pragma unroll
    for (int kk = 0; kk < 8; ++kk) af[kk] = afrag256(As, mi * 16 + lr, kk * 32 + lk);

    f32x4 acc[8];
    #pragma unroll
    for (int f = 0; f < 8; ++f) {
        acc[f] = (f32x4){0.f, 0.f, 0.f, 0.f};
        const unsigned short* wp = Wt + (size_t)(nh * 128 + f * 16 + lr) * 256 + lk;
        #pragma unroll
        for (int kk = 0; kk < 8; ++kk)
            acc[f] = __builtin_amdgcn_mfma_f32_16x16x32_bf16(af[kk], *(const short8*)(wp + kk * 32), acc[f], 0, 0, 0);
    }

    #pragma unroll
    for (int f = 0; f < 8; ++f) {
        int col = nh * 128 + f * 16 + lr;
        float bv = bias[col];
        if (MODE == MODE_VT) {
            int t0 = mi * 16 + mr;
            ull pk = (ull)f2bf(acc[f][0] + bv) | ((ull)f2bf(acc[f][1] + bv) << 16)
                   | ((ull)f2bf(acc[f][2] + bv) << 32) | ((ull)f2bf(acc[f][3] + bv) << 48);
            *(ull*)((unsigned short*)Outp + (size_t)(m0 >> 6) * 16384 + (size_t)col * 64 + t0) = pk;
        } else {
            #pragma unroll
            for (int r = 0; r < 4; ++r) {
                size_t row = (size_t)m0 + mi * 16 + mr + r;
                float v = acc[f][r] + bv;
                if (MODE == MODE_RELU) v = fmaxf(v, 0.f);
                if (MODE == MODE_RES)
                    ((float*)Outp)[row * 256 + col] = v + Res[row * 256 + col];
                else
                    ((unsigned short*)Outp)[row * 256 + col] = f2bf(v);
            }
        }
    }
}

__launch_bounds__(512)
__global__ void attn_kernel(const unsigned short* __restrict__ q,
                            const unsigned short* __restrict__ Kb,
                            const unsigned short* __restrict__ Vtb,
                            unsigned short* __restrict__ upd)
{
    __shared__ unsigned short qA[2][16 * 256];
    __shared__ unsigned short aT[2][16 * 64];
    __shared__ float attn_f[2][8][72];
    const int t = threadIdx.x, lane = t & 63, wave = t >> 6;
    const int b0 = blockIdx.x * 2;

    for (int i = 0; i < 4; ++i) {
        int s = t + 512 * i;
        int bb = s >> 10, row = (s & 1023) >> 6, c4 = (s & 63) * 4;
        ull pk = 0;
        if (row < 8) pk = *(const ull*)(q + ((size_t)(b0 + bb) * 8 + row) * 256 + c4);
        *(ull*)(&qA[bb][row * 256 + (c4 ^ ((row & 7) << 3))]) = pk;
    }
    ((ull*)aT)[t & 511] = 0;
    __syncthreads();

    const int lr = lane & 15, lk = (lane >> 4) * 8, mr = (lane >> 4) * 4;
    const int bb = wave >> 2, wv = wave & 3;
    const int b = b0 + bb;

    {
        short8 af[8];
        #pragma unroll
        for (int kk = 0; kk < 8; ++kk) af[kk] = afrag256(qA[bb], lr, kk * 32 + lk);
        f32x4 acc = (f32x4){0.f, 0.f, 0.f, 0.f};
        const unsigned short* kp = Kb + ((size_t)b * 64 + wv * 16 + lr) * 256 + lk;
        #pragma unroll
        for (int kk = 0; kk < 8; ++kk)
            acc = __builtin_amdgcn_mfma_f32_16x16x32_bf16(af[kk], *(const short8*)(kp + kk * 32), acc, 0, 0, 0);
        #pragma unroll
        for (int r = 0; r < 4; ++r)
            if (mr + r < 8) attn_f[bb][mr + r][wv * 16 + lr] = acc[r] * 0.0625f;
    }
    __syncthreads();

    if (t < 128) {
        int b2 = t >> 6, tok = t & 63;
        float mx = attn_f[b2][0][tok];
        #pragma unroll
        for (int s = 1; s < 8; ++s) mx = fmaxf(mx, attn_f[b2][s][tok]);
        float e[8], den = 0.f;
        #pragma unroll
        for (int s = 0; s < 8; ++s) { e[s] = expf(attn_f[b2][s][tok] - mx); den += e[s]; }
        float inv = 1.f / den;
        #pragma unroll
        for (int s = 0; s < 8; ++s) attn_f[b2][s][tok] = e[s] * inv + 1e-8f;
    }
    __syncthreads();

    #pragma unroll
    for (int j = 0; j < 2; ++j) {
        int id = wave * 2 + j;
        int b3 = id >> 3, s3 = id & 7;
        float v = attn_f[b3][s3][lane];
        float ssum = v;
        #pragma unroll
        for (int m = 32; m >= 1; m >>= 1) ssum += __shfl_xor(ssum, m);
        aT[b3][s3 * 64 + (lane ^ ((s3 & 7) << 3))] = f2bf(v / ssum);
    }
    __syncthreads();

    {
        short8 a0 = afrag64(aT[bb], lr, lk);
        short8 a1 = afrag64(aT[bb], lr, 32 + lk);
        #pragma unroll
        for (int f = 0; f < 4; ++f) {
            int col = wv * 64 + f * 16 + lr;
            const unsigned short* vp = Vtb + (size_t)b * 16384 + (size_t)col * 64;
            f32x4 acc = (f32x4){0.f, 0.f, 0.f, 0.f};
            acc = __builtin_amdgcn_mfma_f32_16x16x32_bf16(a0, *(const short8*)(vp + lk), acc, 0, 0, 0);
            acc = __builtin_amdgcn_mfma_f32_16x16x32_bf16(a1, *(const short8*)(vp + 32 + lk), acc, 0, 0, 0);
            #pragma unroll
            for (int r = 0; r < 4; ++r)
                if (mr + r < 8) upd[((size_t)b * 8 + mr + r) * 256 + col] = f2bf(acc[r]);
        }
    }
}

__launch_bounds__(512)
__global__ void gru_kernel(const unsigned short* __restrict__ upd,
                           const float* __restrict__ ping,
                           const unsigned short* __restrict__ gihb,
                           const unsigned short* __restrict__ ghhb,
                           const float* __restrict__ bih, const float* __restrict__ bhh,
                           float* __restrict__ pong)
{
    __shared__ unsigned short Us[64 * 256], Ss[64 * 256];
    const int t = threadIdx.x, lane = t & 63, wave = t >> 6;
    const int m0 = blockIdx.x * 64, c0 = blockIdx.y * 64;

    for (int i = 0; i < 8; ++i) {
        int s = t + 512 * i;
        int row = s >> 6, c4 = (s & 63) * 4;
        ull pk = *(const ull*)(upd + (size_t)(m0 + row) * 256 + c4);
        *(ull*)(Us + row * 256 + (c4 ^ ((row & 7) << 3))) = pk;
        float4 v = *(const float4*)(ping + (size_t)(m0 + row) * 256 + c4);
        *(ull*)(Ss + row * 256 + (c4 ^ ((row & 7) << 3))) =
            (ull)f2bf(v.x) | ((ull)f2bf(v.y) << 16) | ((ull)f2bf(v.z) << 32) | ((ull)f2bf(v.w) << 48);
    }
    __syncthreads();

    const int lr = lane & 15, lk = (lane >> 4) * 8, mr = (lane >> 4) * 4;
    const int mi = wave & 3, ch = wave >> 2;

    short8 uf[8], sf[8];
    #pragma unroll
    for (int kk = 0; kk < 8; ++kk) {
        uf[kk] = afrag256(Us, mi * 16 + lr, kk * 32 + lk);
        sf[kk] = afrag256(Ss, mi * 16 + lr, kk * 32 + lk);
    }
    f32x4 ax[3][2], ah[3][2];
    #pragma unroll
    for (int g = 0; g < 3; ++g)
    #pragma unroll
    for (int cc = 0; cc < 2; ++cc) {
        ax[g][cc] = (f32x4){0.f, 0.f, 0.f, 0.f};
        ah[g][cc] = (f32x4){0.f, 0.f, 0.f, 0.f};
        int col = c0 + ch * 32 + cc * 16 + lr;
        const unsigned short* bx = gihb + (size_t)(g * 256 + col) * 256 + lk;
        const unsigned short* bh = ghhb + (size_t)(g * 256 + col) * 256 + lk;
        #pragma unroll
        for (int kk = 0; kk < 8; ++kk) {
            ax[g][cc] = __builtin_amdgcn_mfma_f32_16x16x32_bf16(uf[kk], *(const short8*)(bx + kk * 32), ax[g][cc], 0, 0, 0);
            ah[g][cc] = __builtin_amdgcn_mfma_f32_16x16x32_bf16(sf[kk], *(const short8*)(bh + kk * 32), ah[g][cc], 0, 0, 0);
        }
    }
    #pragma unroll
    for (int cc = 0; cc < 2; ++cc) {
        int col = c0 + ch * 32 + cc * 16 + lr;
        float bxr = bih[col], bxz = bih[col + 256], bxn = bih[col + 512];
        float bhr = bhh[col], bhz = bhh[col + 256], bhn = bhh[col + 512];
        #pragma unroll
        for (int r = 0; r < 4; ++r) {
            size_t row = (size_t)m0 + mi * 16 + mr + r;
            float prev = ping[row * 256 + col];
            float rr = sigmoidf_(ax[0][cc][r] + bxr + ah[0][cc][r] + bhr);
            float zz = sigmoidf_(ax[1][cc][r] + bxz + ah[1][cc][r] + bhz);
            float nn = tanhf(ax[2][cc][r] + bxn + rr * (ah[2][cc][r] + bhn));
            pong[row * 256 + col] = (1.f - zz) * nn + zz * prev;
        }
    }
}

extern "C" void kernel_launch(void* const* d_in, const int* in_sizes, int n_in,
                              void* d_out, int out_size, void* d_ws, size_t ws_size,
                              hipStream_t stream) {
    (void)in_sizes; (void)n_in; (void)ws_size; (void)out_size;
    unsigned short* wsb  = (unsigned short*)d_ws;
    unsigned short* bufA = wsb + (1u << 20);
    unsigned short* bufB = bufA + 16777216;
    unsigned short* bufC = bufB + 16777216;
    float* ping = (float*)(bufC + 16777216);
    float* pong = ping + 2097152;
    unsigned short* qbuf   = bufA;
    unsigned short* updbuf = bufA + 2097152;
    unsigned short* hbuf   = bufA + 4194304;

    const unsigned short* f1t  = wsb;
    const unsigned short* f2t  = wsb + 65536;
    const unsigned short* kt   = wsb + 131072;
    const unsigned short* vwt  = wsb + 196608;
    const unsigned short* qt   = wsb + 262144;
    const unsigned short* m1t  = wsb + 327680;
    const unsigned short* m2t  = wsb + 393216;
    const unsigned short* gihb = wsb + 458752;
    const unsigned short* ghhb = wsb + 655360;

    convert_weights<<<dim3(1664), dim3(512), 0, stream>>>(
        (const float*)d_in[6],  (const float*)d_in[8],  (const float*)d_in[14],
        (const float*)d_in[16], (const float*)d_in[12], (const float*)d_in[26],
        (const float*)d_in[28], (const float*)d_in[18], (const float*)d_in[19], wsb);

    slot_init<<<dim3(4096), dim3(512), 0, stream>>>(
        (const float*)d_in[30], (const float*)d_in[31], (const float*)d_in[1], ping);

    pos_ln_kernel<<<dim3(1024), dim3(512), 0, stream>>>(
        (const float*)d_in[0], (const float*)d_in[2], (const float*)d_in[3],
        (const float*)d_in[4], (const float*)d_in[5], bufA);

    gemm64_kernel<MODE_RELU, 0, 0><<<dim3(1024), dim3(512), 0, stream>>>(
        bufA, f1t, (const float*)d_in[7], nullptr, nullptr, bufB, nullptr);
    gemm64_kernel<MODE_RELU, 0, 0><<<dim3(1024), dim3(512), 0, stream>>>(
        bufB, f2t, (const float*)d_in[9], nullptr, nullptr, bufA, nullptr);
    gemm64_kernel<MODE_PLAIN, 1, 0><<<dim3(1024), dim3(512), 0, stream>>>(
        bufA, kt, (const float*)d_in[15], (const float*)d_in[10], (const float*)d_in[11], bufB, nullptr);
    gemm64_kernel<MODE_VT, 1, 0><<<dim3(1024), dim3(512), 0, stream>>>(
        bufA, vwt, (const float*)d_in[17], (const float*)d_in[10], (const float*)d_in[11], bufC, nullptr);

    for (int it = 0; it < 5; ++it) {
        gemm64_kernel<MODE_PLAIN, 1, 1><<<dim3(128), dim3(512), 0, stream>>>(
            ping, qt, (const float*)d_in[13], (const float*)d_in[22], (const float*)d_in[23], qbuf, nullptr);
        attn_kernel<<<dim3(512), dim3(512), 0, stream>>>(qbuf, bufB, bufC, updbuf);
        gru_kernel<<<dim3(128, 4), dim3(512), 0, stream>>>(
            updbuf, ping, gihb, ghhb, (const float*)d_in[20], (const float*)d_in[21], pong);
        gemm64_kernel<MODE_RELU, 1, 1><<<dim3(128), dim3(512), 0, stream>>>(
            pong, m1t, (const float*)d_in[27], (const float*)d_in[24], (const float*)d_in[25], hbuf, nullptr);
        void* dst = (it == 4) ? d_out : (void*)ping;
        gemm64_kernel<MODE_RES, 0, 0><<<dim3(128), dim3(512), 0, stream>>>(
            hbuf, m2t, (const float*)d_in[29], nullptr, nullptr, dst, pong);
    }
}

// Round 5
// 601.923 us; speedup vs baseline: 7.9145x; 1.5580x over previous
//
#include <hip/hip_runtime.h>
#include <math.h>

// ------------------------------------------------------------------
// R5 = R4 with the buffer-lifetime fix: slot_init launches AFTER the
// encoder (its outputs srawb/lnq live in bufA, which gemm_f2ln
// overwrites in full). B=1024, D=256, tok=64, slots=8, iters=5.
// ws (u16 units): W:0..851968  bufA:1<<20  bufB:+16M  bufC(Vt):+32M
// ping/pong f32 after bufC.
// ------------------------------------------------------------------

typedef __attribute__((ext_vector_type(8))) short short8;
typedef __attribute__((ext_vector_type(4))) float f32x4;
typedef unsigned long long ull;

__device__ __forceinline__ unsigned short f2bf(float f) {
    union { float f; unsigned u; } x; x.f = f;
    unsigned r = x.u + 0x7fffu + ((x.u >> 16) & 1u);
    return (unsigned short)(r >> 16);
}
__device__ __forceinline__ float bf2f(unsigned short h) {
    union { unsigned u; float f; } x; x.u = ((unsigned)h) << 16;
    return x.f;
}
__device__ __forceinline__ float sigmoidf_(float x) { return 1.f / (1.f + expf(-x)); }
__device__ __forceinline__ ull pack4(float a, float b, float c, float d) {
    return (ull)f2bf(a) | ((ull)f2bf(b) << 16) | ((ull)f2bf(c) << 32) | ((ull)f2bf(d) << 48);
}
__device__ __forceinline__ short8 afrag256(const unsigned short* buf, int row, int k) {
    return *(const short8*)(buf + row * 256 + (k ^ ((row & 7) << 3)));
}
__device__ __forceinline__ short8 afrag64(const unsigned short* buf, int row, int k) {
    return *(const short8*)(buf + row * 64 + (k ^ ((row & 7) << 3)));
}

// ---------------- weight preconvert (unchanged, verified) ----------------
__global__ void convert_weights(
    const float* __restrict__ f1W, const float* __restrict__ f2W,
    const float* __restrict__ kW,  const float* __restrict__ vW,
    const float* __restrict__ qW,  const float* __restrict__ m1W,
    const float* __restrict__ m2W, const float* __restrict__ gih,
    const float* __restrict__ ghh, unsigned short* __restrict__ out)
{
    int id = blockIdx.x * 512 + threadIdx.x;
    if (id < 7 * 65536) {
        int mi = id >> 16, e = id & 65535;
        int k = e >> 8, n = e & 255;
        const float* src = mi == 0 ? f1W : mi == 1 ? f2W : mi == 2 ? kW :
                           mi == 3 ? vW  : mi == 4 ? qW  : mi == 5 ? m1W : m2W;
        out[mi * 65536 + n * 256 + k] = f2bf(src[e]);
    } else if (id < 851968) {
        int e = id - 7 * 65536;
        const float* src = e < 196608 ? gih : ghh;
        int ee = e < 196608 ? e : e - 196608;
        out[458752 + e] = f2bf(src[ee]);
    }
}

// ---------------- slot init: ping f32 + sraw bf16 + lnq (ns-LN) bf16 ------
__launch_bounds__(512)
__global__ void slot_init(const float* __restrict__ mu, const float* __restrict__ sig,
                          const float* __restrict__ noise,
                          const float* __restrict__ nsw, const float* __restrict__ nsb,
                          float* __restrict__ ping, unsigned short* __restrict__ sraw,
                          unsigned short* __restrict__ lnq)
{
    const int t = threadIdx.x, lane = t & 63, wave = t >> 6;
    const int row = blockIdx.x * 8 + wave;
    const int c = lane * 4;
    float4 n4 = *(const float4*)(noise + (size_t)row * 256 + c);
    float4 m4 = *(const float4*)(mu + c);
    float4 g4 = *(const float4*)(sig + c);
    float v0 = m4.x + expf(0.5f * g4.x) * n4.x;
    float v1 = m4.y + expf(0.5f * g4.y) * n4.y;
    float v2 = m4.z + expf(0.5f * g4.z) * n4.z;
    float v3 = m4.w + expf(0.5f * g4.w) * n4.w;
    float s1 = v0 + v1 + v2 + v3;
    float s2 = v0 * v0 + v1 * v1 + v2 * v2 + v3 * v3;
    #pragma unroll
    for (int m = 32; m >= 1; m >>= 1) { s1 += __shfl_xor(s1, m); s2 += __shfl_xor(s2, m); }
    float mu_ = s1 * (1.f / 256.f);
    float rs_ = rsqrtf(s2 * (1.f / 256.f) - mu_ * mu_ + 1e-5f);
    float4 w4 = *(const float4*)(nsw + c);
    float4 b4 = *(const float4*)(nsb + c);
    *(float4*)(ping + (size_t)row * 256 + c) = make_float4(v0, v1, v2, v3);
    *(ull*)(sraw + (size_t)row * 256 + c) = pack4(v0, v1, v2, v3);
    *(ull*)(lnq + (size_t)row * 256 + c) = pack4(
        (v0 - mu_) * rs_ * w4.x + b4.x, (v1 - mu_) * rs_ * w4.y + b4.y,
        (v2 - mu_) * rs_ * w4.z + b4.z, (v3 - mu_) * rs_ * w4.w + b4.w);
}

// ---------------- pos-embed + global enln (unchanged) ----------------
__launch_bounds__(512)
__global__ void pos_ln_kernel(const float* __restrict__ g_in,
                              const float* __restrict__ g_posW, const float* __restrict__ g_posb,
                              const float* __restrict__ g_enw,  const float* __restrict__ g_enb,
                              unsigned short* __restrict__ outA)
{
    __shared__ unsigned short xs[64 * 256];
    __shared__ float red[16];
    const int b = blockIdx.x, t = threadIdx.x, lane = t & 63, wave = t >> 6;

    const float* inb = g_in + (size_t)b * 16384;
    float psum = 0.f, psq = 0.f;
    for (int i = 0; i < 8; ++i) {
        int idx4 = i * 512 + t;
        int d = idx4 >> 4;
        int r0 = (idx4 & 15) << 2;
        float4 v = ((const float4*)inb)[idx4];
        float pw0 = g_posW[d], pw1 = g_posW[256 + d], pw2 = g_posW[512 + d], pw3 = g_posW[768 + d];
        float pb = g_posb[d];
        float vals[4] = {v.x, v.y, v.z, v.w};
        #pragma unroll
        for (int q = 0; q < 4; ++q) {
            int r = r0 + q;
            float fh = (float)(r >> 3) * (1.f / 7.f);
            float fw = (float)(r & 7) * (1.f / 7.f);
            float x = vals[q] + fh * pw0 + fw * pw1 + (1.f - fh) * pw2 + (1.f - fw) * pw3 + pb;
            xs[r * 256 + (d ^ ((r & 7) << 3))] = f2bf(x);
            psum += x; psq += x * x;
        }
    }
    #pragma unroll
    for (int m = 32; m >= 1; m >>= 1) { psum += __shfl_xor(psum, m); psq += __shfl_xor(psq, m); }
    if (lane == 0) { red[wave] = psum; red[8 + wave] = psq; }
    __syncthreads();
    {
        float tsum = 0.f, tsq = 0.f;
        #pragma unroll
        for (int w2 = 0; w2 < 8; ++w2) { tsum += red[w2]; tsq += red[8 + w2]; }
        float mu = tsum * (1.f / 16384.f);
        float rs = rsqrtf(tsq * (1.f / 16384.f) - mu * mu + 1e-5f);
        int row = t >> 3, c0 = (t & 7) * 32;
        for (int j = 0; j < 8; ++j) {
            int c = c0 + j * 4;
            ull* p = (ull*)(xs + row * 256 + (c ^ ((row & 7) << 3)));
            ull pk = *p;
            float4 w4 = *(const float4*)&g_enw[row * 256 + c];
            float4 b4 = *(const float4*)&g_enb[row * 256 + c];
            float v0 = (bf2f((unsigned short)pk)         - mu) * rs * w4.x + b4.x;
            float v1 = (bf2f((unsigned short)(pk >> 16)) - mu) * rs * w4.y + b4.y;
            float v2 = (bf2f((unsigned short)(pk >> 32)) - mu) * rs * w4.z + b4.z;
            float v3 = (bf2f((unsigned short)(pk >> 48)) - mu) * rs * w4.w + b4.w;
            *p = pack4(v0, v1, v2, v3);
        }
    }
    __syncthreads();
    for (int i = 0; i < 8; ++i) {
        int s = t + 512 * i;
        int row = s >> 6, c4 = (s & 63) * 4;
        ull pk = *(const ull*)(xs + row * 256 + (c4 ^ ((row & 7) << 3)));
        *(ull*)(outA + (size_t)b * 16384 + row * 256 + c4) = pk;
    }
}

// ---------------- register-weight streaming GEMM core -------------------
#define GEMM_CORE_PROLOG(Wt, bias)                                              \
    const int t = threadIdx.x, lane = t & 63, wave = t >> 6;                    \
    const int lr = lane & 15, lk = (lane >> 4) * 8, mr = (lane >> 4) * 4;       \
    const int wc = wave * 32;                                                   \
    short8 w0[8], w1[8];                                                        \
    {                                                                           \
        const unsigned short* wp0 = Wt + (size_t)(wc + lr) * 256 + lk;          \
        const unsigned short* wp1 = Wt + (size_t)(wc + 16 + lr) * 256 + lk;     \
        _Pragma("unroll")                                                       \
        for (int kk = 0; kk < 8; ++kk) {                                        \
            w0[kk] = *(const short8*)(wp0 + kk * 32);                           \
            w1[kk] = *(const short8*)(wp1 + kk * 32);                           \
        }                                                                       \
    }                                                                           \
    const float b0 = bias[wc + lr], b1 = bias[wc + 16 + lr];

#define GEMM_CORE_TILE(A, tile, acc0, acc1)                                     \
    f32x4 acc0 = (f32x4){0.f,0.f,0.f,0.f}, acc1 = (f32x4){0.f,0.f,0.f,0.f};     \
    {                                                                           \
        const unsigned short* ap = A + (size_t)((tile) * 16 + lr) * 256 + lk;   \
        short8 a[8];                                                            \
        _Pragma("unroll")                                                       \
        for (int kk = 0; kk < 8; ++kk) a[kk] = *(const short8*)(ap + kk * 32);  \
        _Pragma("unroll")                                                       \
        for (int kk = 0; kk < 8; ++kk) {                                        \
            acc0 = __builtin_amdgcn_mfma_f32_16x16x32_bf16(a[kk], w0[kk], acc0, 0, 0, 0); \
            acc1 = __builtin_amdgcn_mfma_f32_16x16x32_bf16(a[kk], w1[kk], acc1, 0, 0, 0); \
        }                                                                       \
    }

template<int TPB, int RELU>
__launch_bounds__(512)
__global__ void gemm_rw(const unsigned short* __restrict__ A,
                        const unsigned short* __restrict__ Wt,
                        const float* __restrict__ bias,
                        unsigned short* __restrict__ Out)
{
    GEMM_CORE_PROLOG(Wt, bias)
    for (int i = 0; i < TPB; ++i) {
        int tile = blockIdx.x * TPB + i;
        GEMM_CORE_TILE(A, tile, acc0, acc1)
        #pragma unroll
        for (int r = 0; r < 4; ++r) {
            size_t row = (size_t)tile * 16 + mr + r;
            float v0 = acc0[r] + b0, v1 = acc1[r] + b1;
            if (RELU) { v0 = fmaxf(v0, 0.f); v1 = fmaxf(v1, 0.f); }
            Out[row * 256 + wc + lr]      = f2bf(v0);
            Out[row * 256 + wc + 16 + lr] = f2bf(v1);
        }
    }
}

// V^T variant: Vt[b][col][tok]
template<int TPB>
__launch_bounds__(512)
__global__ void gemm_vt(const unsigned short* __restrict__ A,
                        const unsigned short* __restrict__ Wt,
                        const float* __restrict__ bias,
                        unsigned short* __restrict__ Vt)
{
    GEMM_CORE_PROLOG(Wt, bias)
    for (int i = 0; i < TPB; ++i) {
        int tile = blockIdx.x * TPB + i;
        GEMM_CORE_TILE(A, tile, acc0, acc1)
        int bidx = tile >> 2;
        int t0 = (tile & 3) * 16 + mr;
        *(ull*)(Vt + (size_t)bidx * 16384 + (size_t)(wc + lr) * 64 + t0) =
            pack4(acc0[0] + b0, acc0[1] + b0, acc0[2] + b0, acc0[3] + b0);
        *(ull*)(Vt + (size_t)bidx * 16384 + (size_t)(wc + 16 + lr) * 64 + t0) =
            pack4(acc1[0] + b1, acc1[1] + b1, acc1[2] + b1, acc1[3] + b1);
    }
}

// f2 variant: relu + per-row LN(ni) fused via LDS
__launch_bounds__(512)
__global__ void gemm_f2ln(const unsigned short* __restrict__ A,
                          const unsigned short* __restrict__ Wt,
                          const float* __restrict__ bias,
                          const float* __restrict__ niw, const float* __restrict__ nib,
                          unsigned short* __restrict__ Out)
{
    __shared__ unsigned short xl[128 * 256];
    GEMM_CORE_PROLOG(Wt, bias)
    for (int i = 0; i < 8; ++i) {
        int tile = blockIdx.x * 8 + i;
        GEMM_CORE_TILE(A, tile, acc0, acc1)
        #pragma unroll
        for (int r = 0; r < 4; ++r) {
            int lrow = i * 16 + mr + r;
            xl[lrow * 256 + ((wc + lr)      ^ ((lrow & 7) << 3))] = f2bf(fmaxf(acc0[r] + b0, 0.f));
            xl[lrow * 256 + ((wc + 16 + lr) ^ ((lrow & 7) << 3))] = f2bf(fmaxf(acc1[r] + b1, 0.f));
        }
    }
    __syncthreads();
    const float4 w4 = *(const float4*)(niw + lane * 4);
    const float4 b4 = *(const float4*)(nib + lane * 4);
    for (int rr = 0; rr < 16; ++rr) {
        int row = wave * 16 + rr;
        ull pk = *(const ull*)(xl + row * 256 + ((lane * 4) ^ ((row & 7) << 3)));
        float v0 = bf2f((unsigned short)pk),         v1 = bf2f((unsigned short)(pk >> 16));
        float v2 = bf2f((unsigned short)(pk >> 32)), v3 = bf2f((unsigned short)(pk >> 48));
        float s1 = v0 + v1 + v2 + v3;
        float s2 = v0 * v0 + v1 * v1 + v2 * v2 + v3 * v3;
        #pragma unroll
        for (int m = 32; m >= 1; m >>= 1) { s1 += __shfl_xor(s1, m); s2 += __shfl_xor(s2, m); }
        float mu_ = s1 * (1.f / 256.f);
        float rs_ = rsqrtf(s2 * (1.f / 256.f) - mu_ * mu_ + 1e-5f);
        *(ull*)(Out + ((size_t)blockIdx.x * 128 + row) * 256 + lane * 4) = pack4(
            (v0 - mu_) * rs_ * w4.x + b4.x, (v1 - mu_) * rs_ * w4.y + b4.y,
            (v2 - mu_) * rs_ * w4.z + b4.z, (v3 - mu_) * rs_ * w4.w + b4.w);
    }
}

// m2 variant: + residual + writes {f32 slots, ns-LN bf16, raw bf16}
__launch_bounds__(512)
__global__ void gemm_m2(const unsigned short* __restrict__ A,
                        const unsigned short* __restrict__ Wt,
                        const float* __restrict__ bias,
                        const float* __restrict__ res,
                        const float* __restrict__ nsw, const float* __restrict__ nsb,
                        float* __restrict__ outf, unsigned short* __restrict__ lnq,
                        unsigned short* __restrict__ sraw)
{
    __shared__ float sl[32][256];
    GEMM_CORE_PROLOG(Wt, bias)
    const int m0 = blockIdx.x * 32;
    for (int i = 0; i < 2; ++i) {
        int tile = blockIdx.x * 2 + i;
        GEMM_CORE_TILE(A, tile, acc0, acc1)
        #pragma unroll
        for (int r = 0; r < 4; ++r) {
            int lrow = i * 16 + mr + r;
            size_t grow = (size_t)m0 + lrow;
            sl[lrow][wc + lr]      = acc0[r] + b0 + res[grow * 256 + wc + lr];
            sl[lrow][wc + 16 + lr] = acc1[r] + b1 + res[grow * 256 + wc + 16 + lr];
        }
    }
    __syncthreads();
    const float4 w4 = *(const float4*)(nsw + lane * 4);
    const float4 b4 = *(const float4*)(nsb + lane * 4);
    #pragma unroll
    for (int rr = 0; rr < 4; ++rr) {
        int row = wave * 4 + rr;
        float4 v = *(const float4*)&sl[row][lane * 4];
        float s1 = v.x + v.y + v.z + v.w;
        float s2 = v.x * v.x + v.y * v.y + v.z * v.z + v.w * v.w;
        #pragma unroll
        for (int m = 32; m >= 1; m >>= 1) { s1 += __shfl_xor(s1, m); s2 += __shfl_xor(s2, m); }
        float mu_ = s1 * (1.f / 256.f);
        float rs_ = rsqrtf(s2 * (1.f / 256.f) - mu_ * mu_ + 1e-5f);
        size_t off = ((size_t)m0 + row) * 256 + lane * 4;
        *(float4*)(outf + off) = v;
        *(ull*)(sraw + off) = pack4(v.x, v.y, v.z, v.w);
        *(ull*)(lnq + off) = pack4(
            (v.x - mu_) * rs_ * w4.x + b4.x, (v.y - mu_) * rs_ * w4.y + b4.y,
            (v.z - mu_) * rs_ * w4.z + b4.z, (v.w - mu_) * rs_ * w4.w + b4.w);
    }
}

// ---------------- attention (unchanged from R3) ----------------
__launch_bounds__(512)
__global__ void attn_kernel(const unsigned short* __restrict__ q,
                            const unsigned short* __restrict__ Kb,
                            const unsigned short* __restrict__ Vtb,
                            unsigned short* __restrict__ upd)
{
    __shared__ unsigned short qA[2][16 * 256];
    __shared__ unsigned short aT[2][16 * 64];
    __shared__ float attn_f[2][8][72];
    const int t = threadIdx.x, lane = t & 63, wave = t >> 6;
    const int b0 = blockIdx.x * 2;

    for (int i = 0; i < 4; ++i) {
        int s = t + 512 * i;
        int bb = s >> 10, row = (s & 1023) >> 6, c4 = (s & 63) * 4;
        ull pk = 0;
        if (row < 8) pk = *(const ull*)(q + ((size_t)(b0 + bb) * 8 + row) * 256 + c4);
        *(ull*)(&qA[bb][row * 256 + (c4 ^ ((row & 7) << 3))]) = pk;
    }
    ((ull*)aT)[t & 511] = 0;
    __syncthreads();

    const int lr = lane & 15, lk = (lane >> 4) * 8, mr = (lane >> 4) * 4;
    const int bb = wave >> 2, wv = wave & 3;
    const int b = b0 + bb;

    {
        short8 af[8];
        #pragma unroll
        for (int kk = 0; kk < 8; ++kk) af[kk] = afrag256(qA[bb], lr, kk * 32 + lk);
        f32x4 acc = (f32x4){0.f, 0.f, 0.f, 0.f};
        const unsigned short* kp = Kb + ((size_t)b * 64 + wv * 16 + lr) * 256 + lk;
        #pragma unroll
        for (int kk = 0; kk < 8; ++kk)
            acc = __builtin_amdgcn_mfma_f32_16x16x32_bf16(af[kk], *(const short8*)(kp + kk * 32), acc, 0, 0, 0);
        #pragma unroll
        for (int r = 0; r < 4; ++r)
            if (mr + r < 8) attn_f[bb][mr + r][wv * 16 + lr] = acc[r] * 0.0625f;
    }
    __syncthreads();

    if (t < 128) {
        int b2 = t >> 6, tok = t & 63;
        float mx = attn_f[b2][0][tok];
        #pragma unroll
        for (int s = 1; s < 8; ++s) mx = fmaxf(mx, attn_f[b2][s][tok]);
        float e[8], den = 0.f;
        #pragma unroll
        for (int s = 0; s < 8; ++s) { e[s] = expf(attn_f[b2][s][tok] - mx); den += e[s]; }
        float inv = 1.f / den;
        #pragma unroll
        for (int s = 0; s < 8; ++s) attn_f[b2][s][tok] = e[s] * inv + 1e-8f;
    }
    __syncthreads();

    #pragma unroll
    for (int j = 0; j < 2; ++j) {
        int id = wave * 2 + j;
        int b3 = id >> 3, s3 = id & 7;
        float v = attn_f[b3][s3][lane];
        float ssum = v;
        #pragma unroll
        for (int m = 32; m >= 1; m >>= 1) ssum += __shfl_xor(ssum, m);
        aT[b3][s3 * 64 + (lane ^ ((s3 & 7) << 3))] = f2bf(v / ssum);
    }
    __syncthreads();

    {
        short8 a0 = afrag64(aT[bb], lr, lk);
        short8 a1 = afrag64(aT[bb], lr, 32 + lk);
        #pragma unroll
        for (int f = 0; f < 4; ++f) {
            int col = wv * 64 + f * 16 + lr;
            const unsigned short* vp = Vtb + (size_t)b * 16384 + (size_t)col * 64;
            f32x4 acc = (f32x4){0.f, 0.f, 0.f, 0.f};
            acc = __builtin_amdgcn_mfma_f32_16x16x32_bf16(a0, *(const short8*)(vp + lk), acc, 0, 0, 0);
            acc = __builtin_amdgcn_mfma_f32_16x16x32_bf16(a1, *(const short8*)(vp + 32 + lk), acc, 0, 0, 0);
            #pragma unroll
            for (int r = 0; r < 4; ++r)
                if (mr + r < 8) upd[((size_t)b * 8 + mr + r) * 256 + col] = f2bf(acc[r]);
        }
    }
}

// ---------------- GRU: all 6 gate-GEMMs + nonlin + pf-LN fused -----------
__launch_bounds__(512, 2)
__global__ void gru_kernel(const unsigned short* __restrict__ upd,
                           const unsigned short* __restrict__ srawb,
                           const float* __restrict__ ping,
                           const unsigned short* __restrict__ gihb,
                           const unsigned short* __restrict__ ghhb,
                           const float* __restrict__ bih, const float* __restrict__ bhh,
                           const float* __restrict__ pfw, const float* __restrict__ pfb,
                           float* __restrict__ pong, unsigned short* __restrict__ ponglnq)
{
    __shared__ unsigned short Us[32 * 256], Ss[32 * 256];
    __shared__ float hl[32][256];
    const int t = threadIdx.x, lane = t & 63, wave = t >> 6;
    const int m0 = blockIdx.x * 32;

    for (int i = 0; i < 4; ++i) {
        int id = t + 512 * i;
        int row = id >> 6, c4 = (id & 63) * 4;
        size_t g = ((size_t)m0 + row) * 256 + c4;
        *(ull*)(Us + row * 256 + (c4 ^ ((row & 7) << 3))) = *(const ull*)(upd + g);
        *(ull*)(Ss + row * 256 + (c4 ^ ((row & 7) << 3))) = *(const ull*)(srawb + g);
    }
    __syncthreads();

    const int lr = lane & 15, lk = (lane >> 4) * 8, mr = (lane >> 4) * 4;
    const int wc = wave * 32;

    f32x4 aR[2][2], aZ[2][2], aN[2][2], aH[2][2];
    #pragma unroll
    for (int cf = 0; cf < 2; ++cf)
        #pragma unroll
        for (int m = 0; m < 2; ++m) {
            aR[cf][m] = (f32x4){0.f,0.f,0.f,0.f}; aZ[cf][m] = (f32x4){0.f,0.f,0.f,0.f};
            aN[cf][m] = (f32x4){0.f,0.f,0.f,0.f}; aH[cf][m] = (f32x4){0.f,0.f,0.f,0.f};
        }

    #pragma unroll
    for (int g = 0; g < 3; ++g) {
        #pragma unroll
        for (int cf = 0; cf < 2; ++cf) {
            int col = wc + cf * 16 + lr;
            const unsigned short* px = gihb + (size_t)(g * 256 + col) * 256 + lk;
            const unsigned short* ph = ghhb + (size_t)(g * 256 + col) * 256 + lk;
            short8 wx[8], wh[8];
            #pragma unroll
            for (int kk = 0; kk < 8; ++kk) {
                wx[kk] = *(const short8*)(px + kk * 32);
                wh[kk] = *(const short8*)(ph + kk * 32);
            }
            #pragma unroll
            for (int m = 0; m < 2; ++m) {
                #pragma unroll
                for (int kk = 0; kk < 8; ++kk) {
                    short8 u = afrag256(Us, m * 16 + lr, kk * 32 + lk);
                    short8 s = afrag256(Ss, m * 16 + lr, kk * 32 + lk);
                    if (g == 0) {
                        aR[cf][m] = __builtin_amdgcn_mfma_f32_16x16x32_bf16(u, wx[kk], aR[cf][m], 0, 0, 0);
                        aR[cf][m] = __builtin_amdgcn_mfma_f32_16x16x32_bf16(s, wh[kk], aR[cf][m], 0, 0, 0);
                    } else if (g == 1) {
                        aZ[cf][m] = __builtin_amdgcn_mfma_f32_16x16x32_bf16(u, wx[kk], aZ[cf][m], 0, 0, 0);
                        aZ[cf][m] = __builtin_amdgcn_mfma_f32_16x16x32_bf16(s, wh[kk], aZ[cf][m], 0, 0, 0);
                    } else {
                        aN[cf][m] = __builtin_amdgcn_mfma_f32_16x16x32_bf16(u, wx[kk], aN[cf][m], 0, 0, 0);
                        aH[cf][m] = __builtin_amdgcn_mfma_f32_16x16x32_bf16(s, wh[kk], aH[cf][m], 0, 0, 0);
                    }
                }
            }
        }
    }

    #pragma unroll
    for (int cf = 0; cf < 2; ++cf) {
        int col = wc + cf * 16 + lr;
        float bR  = bih[col] + bhh[col];
        float bZ  = bih[col + 256] + bhh[col + 256];
        float bXN = bih[col + 512], bHN = bhh[col + 512];
        #pragma unroll
        for (int m = 0; m < 2; ++m)
            #pragma unroll
            for (int r = 0; r < 4; ++r) {
                int row = m * 16 + mr + r;
                float prev = ping[((size_t)m0 + row) * 256 + col];
                float rr = sigmoidf_(aR[cf][m][r] + bR);
                float zz = sigmoidf_(aZ[cf][m][r] + bZ);
                float nn = tanhf(aN[cf][m][r] + bXN + rr * (aH[cf][m][r] + bHN));
                hl[row][col] = (1.f - zz) * nn + zz * prev;
            }
    }
    __syncthreads();

    const float4 w4 = *(const float4*)(pfw + lane * 4);
    const float4 b4 = *(const float4*)(pfb + lane * 4);
    #pragma unroll
    for (int rr = 0; rr < 4; ++rr) {
        int row = wave * 4 + rr;
        float4 v = *(const float4*)&hl[row][lane * 4];
        float s1 = v.x + v.y + v.z + v.w;
        float s2 = v.x * v.x + v.y * v.y + v.z * v.z + v.w * v.w;
        #pragma unroll
        for (int m = 32; m >= 1; m >>= 1) { s1 += __shfl_xor(s1, m); s2 += __shfl_xor(s2, m); }
        float mu_ = s1 * (1.f / 256.f);
        float rs_ = rsqrtf(s2 * (1.f / 256.f) - mu_ * mu_ + 1e-5f);
        size_t off = ((size_t)m0 + row) * 256 + lane * 4;
        *(float4*)(pong + off) = v;
        *(ull*)(ponglnq + off) = pack4(
            (v.x - mu_) * rs_ * w4.x + b4.x, (v.y - mu_) * rs_ * w4.y + b4.y,
            (v.z - mu_) * rs_ * w4.z + b4.z, (v.w - mu_) * rs_ * w4.w + b4.w);
    }
}

// ------------------------------------------------------------------
extern "C" void kernel_launch(void* const* d_in, const int* in_sizes, int n_in,
                              void* d_out, int out_size, void* d_ws, size_t ws_size,
                              hipStream_t stream) {
    (void)in_sizes; (void)n_in; (void)ws_size; (void)out_size;
    unsigned short* wsb  = (unsigned short*)d_ws;
    unsigned short* bufA = wsb + (1u << 20);
    unsigned short* bufB = bufA + 16777216;          // f1-out, then K
    unsigned short* bufC = bufB + 16777216;          // V^T
    float* ping = (float*)(bufC + 16777216);
    float* pong = ping + 2097152;
    unsigned short* qbuf    = bufA;                  // bufA dead after encoder
    unsigned short* updbuf  = bufA + 2097152;
    unsigned short* hbuf    = bufA + 4194304;
    unsigned short* srawb   = bufA + 6291456;
    unsigned short* lnq     = bufA + 8388608;
    unsigned short* ponglnq = bufA + 10485760;

    const unsigned short* f1t  = wsb;
    const unsigned short* f2t  = wsb + 65536;
    const unsigned short* kt   = wsb + 131072;
    const unsigned short* vwt  = wsb + 196608;
    const unsigned short* qt   = wsb + 262144;
    const unsigned short* m1t  = wsb + 327680;
    const unsigned short* m2t  = wsb + 393216;
    const unsigned short* gihb = wsb + 458752;
    const unsigned short* ghhb = wsb + 655360;

    convert_weights<<<dim3(1664), dim3(512), 0, stream>>>(
        (const float*)d_in[6],  (const float*)d_in[8],  (const float*)d_in[14],
        (const float*)d_in[16], (const float*)d_in[12], (const float*)d_in[26],
        (const float*)d_in[28], (const float*)d_in[18], (const float*)d_in[19], wsb);

    pos_ln_kernel<<<dim3(1024), dim3(512), 0, stream>>>(
        (const float*)d_in[0], (const float*)d_in[2], (const float*)d_in[3],
        (const float*)d_in[4], (const float*)d_in[5], bufA);

    gemm_rw<8, 1><<<dim3(512), dim3(512), 0, stream>>>(bufA, f1t, (const float*)d_in[7], bufB);
    gemm_f2ln<<<dim3(512), dim3(512), 0, stream>>>(bufB, f2t, (const float*)d_in[9],
        (const float*)d_in[10], (const float*)d_in[11], bufA);
    gemm_rw<8, 0><<<dim3(512), dim3(512), 0, stream>>>(bufA, kt, (const float*)d_in[15], bufB);
    gemm_vt<8><<<dim3(512), dim3(512), 0, stream>>>(bufA, vwt, (const float*)d_in[17], bufC);

    // slot_init AFTER the encoder: srawb/lnq live inside bufA, which the
    // encoder (gemm_f2ln output, kt/vt inputs) owns until gemm_vt is done.
    slot_init<<<dim3(1024), dim3(512), 0, stream>>>(
        (const float*)d_in[30], (const float*)d_in[31], (const float*)d_in[1],
        (const float*)d_in[22], (const float*)d_in[23], ping, srawb, lnq);

    for (int it = 0; it < 5; ++it) {
        gemm_rw<2, 0><<<dim3(256), dim3(512), 0, stream>>>(lnq, qt, (const float*)d_in[13], qbuf);
        attn_kernel<<<dim3(512), dim3(512), 0, stream>>>(qbuf, bufB, bufC, updbuf);
        gru_kernel<<<dim3(256), dim3(512), 0, stream>>>(
            updbuf, srawb, ping, gihb, ghhb,
            (const float*)d_in[20], (const float*)d_in[21],
            (const float*)d_in[24], (const float*)d_in[25], pong, ponglnq);
        gemm_rw<2, 1><<<dim3(256), dim3(512), 0, stream>>>(ponglnq, m1t, (const float*)d_in[27], hbuf);
        float* outf = (it == 4) ? (float*)d_out : ping;
        gemm_m2<<<dim3(256), dim3(512), 0, stream>>>(
            hbuf, m2t, (const float*)d_in[29], pong,
            (const float*)d_in[22], (const float*)d_in[23], outf, lnq, srawb);
    }
}

// Round 6
// 440.746 us; speedup vs baseline: 10.8087x; 1.3657x over previous
//
#include <hip/hip_runtime.h>
#include <math.h>

// ------------------------------------------------------------------
// R6: fused-phase version. 9 dispatches total:
//   convert_weights, enc1 (pos+enLN+f1), enc2 (f2+niLN+K+V),
//   slot_init, 5 x iter_kernel (q+attn+GRU+MLP+LN, in-place state).
// B=1024, D=256, tok=64, slots=8, iters=5.
// ws (u16): W:0..851968  bufB:1<<20 (f1out)  ks:+16M  vt:+16M
//           ping f32 / sraw / lnq after.
// ------------------------------------------------------------------

typedef __attribute__((ext_vector_type(8))) short short8;
typedef __attribute__((ext_vector_type(4))) float f32x4;
typedef unsigned long long ull;

__device__ __forceinline__ unsigned short f2bf(float f) {
    union { float f; unsigned u; } x; x.f = f;
    unsigned r = x.u + 0x7fffu + ((x.u >> 16) & 1u);
    return (unsigned short)(r >> 16);
}
__device__ __forceinline__ float bf2f(unsigned short h) {
    union { unsigned u; float f; } x; x.u = ((unsigned)h) << 16;
    return x.f;
}
__device__ __forceinline__ float sigmoidf_(float x) { return 1.f / (1.f + expf(-x)); }
__device__ __forceinline__ ull pack4(float a, float b, float c, float d) {
    return (ull)f2bf(a) | ((ull)f2bf(b) << 16) | ((ull)f2bf(c) << 32) | ((ull)f2bf(d) << 48);
}
__device__ __forceinline__ short8 afrag256(const unsigned short* buf, int row, int k) {
    return *(const short8*)(buf + row * 256 + (k ^ ((row & 7) << 3)));
}
__device__ __forceinline__ short8 afrag64(const unsigned short* buf, int row, int k) {
    return *(const short8*)(buf + row * 64 + (k ^ ((row & 7) << 3)));
}

// ---------------- weight preconvert (verified) ----------------
__global__ void convert_weights(
    const float* __restrict__ f1W, const float* __restrict__ f2W,
    const float* __restrict__ kW,  const float* __restrict__ vW,
    const float* __restrict__ qW,  const float* __restrict__ m1W,
    const float* __restrict__ m2W, const float* __restrict__ gih,
    const float* __restrict__ ghh, unsigned short* __restrict__ out)
{
    int id = blockIdx.x * 512 + threadIdx.x;
    if (id < 7 * 65536) {
        int mi = id >> 16, e = id & 65535;
        int k = e >> 8, n = e & 255;
        const float* src = mi == 0 ? f1W : mi == 1 ? f2W : mi == 2 ? kW :
                           mi == 3 ? vW  : mi == 4 ? qW  : mi == 5 ? m1W : m2W;
        out[mi * 65536 + n * 256 + k] = f2bf(src[e]);
    } else if (id < 851968) {
        int e = id - 7 * 65536;
        const float* src = e < 196608 ? gih : ghh;
        int ee = e < 196608 ? e : e - 196608;
        out[458752 + e] = f2bf(src[ee]);
    }
}

// ---------------- slot init (verified) ----------------
__launch_bounds__(512)
__global__ void slot_init(const float* __restrict__ mu, const float* __restrict__ sig,
                          const float* __restrict__ noise,
                          const float* __restrict__ nsw, const float* __restrict__ nsb,
                          float* __restrict__ ping, unsigned short* __restrict__ sraw,
                          unsigned short* __restrict__ lnq)
{
    const int t = threadIdx.x, lane = t & 63, wave = t >> 6;
    const int row = blockIdx.x * 8 + wave;
    const int c = lane * 4;
    float4 n4 = *(const float4*)(noise + (size_t)row * 256 + c);
    float4 m4 = *(const float4*)(mu + c);
    float4 g4 = *(const float4*)(sig + c);
    float v0 = m4.x + expf(0.5f * g4.x) * n4.x;
    float v1 = m4.y + expf(0.5f * g4.y) * n4.y;
    float v2 = m4.z + expf(0.5f * g4.z) * n4.z;
    float v3 = m4.w + expf(0.5f * g4.w) * n4.w;
    float s1 = v0 + v1 + v2 + v3;
    float s2 = v0 * v0 + v1 * v1 + v2 * v2 + v3 * v3;
    #pragma unroll
    for (int m = 32; m >= 1; m >>= 1) { s1 += __shfl_xor(s1, m); s2 += __shfl_xor(s2, m); }
    float mu_ = s1 * (1.f / 256.f);
    float rs_ = rsqrtf(s2 * (1.f / 256.f) - mu_ * mu_ + 1e-5f);
    float4 w4 = *(const float4*)(nsw + c);
    float4 b4 = *(const float4*)(nsb + c);
    *(float4*)(ping + (size_t)row * 256 + c) = make_float4(v0, v1, v2, v3);
    *(ull*)(sraw + (size_t)row * 256 + c) = pack4(v0, v1, v2, v3);
    *(ull*)(lnq + (size_t)row * 256 + c) = pack4(
        (v0 - mu_) * rs_ * w4.x + b4.x, (v1 - mu_) * rs_ * w4.y + b4.y,
        (v2 - mu_) * rs_ * w4.z + b4.z, (v3 - mu_) * rs_ * w4.w + b4.w);
}

// ---------------- enc1: pos-embed + global enln + f1(relu) ----------------
__launch_bounds__(512)
__global__ void enc1_kernel(const float* __restrict__ g_in,
                            const float* __restrict__ g_posW, const float* __restrict__ g_posb,
                            const float* __restrict__ g_enw,  const float* __restrict__ g_enb,
                            const unsigned short* __restrict__ f1t,
                            const float* __restrict__ f1b,
                            unsigned short* __restrict__ outB)
{
    __shared__ unsigned short xs[64 * 256];
    __shared__ float red[16];
    const int b = blockIdx.x, t = threadIdx.x, lane = t & 63, wave = t >> 6;

    // ---- pos + stats (verified pos_ln body) ----
    const float* inb = g_in + (size_t)b * 16384;
    float psum = 0.f, psq = 0.f;
    for (int i = 0; i < 8; ++i) {
        int idx4 = i * 512 + t;
        int d = idx4 >> 4;
        int r0 = (idx4 & 15) << 2;
        float4 v = ((const float4*)inb)[idx4];
        float pw0 = g_posW[d], pw1 = g_posW[256 + d], pw2 = g_posW[512 + d], pw3 = g_posW[768 + d];
        float pb = g_posb[d];
        float vals[4] = {v.x, v.y, v.z, v.w};
        #pragma unroll
        for (int q = 0; q < 4; ++q) {
            int r = r0 + q;
            float fh = (float)(r >> 3) * (1.f / 7.f);
            float fw = (float)(r & 7) * (1.f / 7.f);
            float x = vals[q] + fh * pw0 + fw * pw1 + (1.f - fh) * pw2 + (1.f - fw) * pw3 + pb;
            xs[r * 256 + (d ^ ((r & 7) << 3))] = f2bf(x);
            psum += x; psq += x * x;
        }
    }
    #pragma unroll
    for (int m = 32; m >= 1; m >>= 1) { psum += __shfl_xor(psum, m); psq += __shfl_xor(psq, m); }
    if (lane == 0) { red[wave] = psum; red[8 + wave] = psq; }
    __syncthreads();
    // ---- global LN in LDS (verified) ----
    {
        float tsum = 0.f, tsq = 0.f;
        #pragma unroll
        for (int w2 = 0; w2 < 8; ++w2) { tsum += red[w2]; tsq += red[8 + w2]; }
        float mu = tsum * (1.f / 16384.f);
        float rs = rsqrtf(tsq * (1.f / 16384.f) - mu * mu + 1e-5f);
        int row = t >> 3, c0 = (t & 7) * 32;
        for (int j = 0; j < 8; ++j) {
            int c = c0 + j * 4;
            ull* p = (ull*)(xs + row * 256 + (c ^ ((row & 7) << 3)));
            ull pk = *p;
            float4 w4 = *(const float4*)&g_enw[row * 256 + c];
            float4 b4 = *(const float4*)&g_enb[row * 256 + c];
            float v0 = (bf2f((unsigned short)pk)         - mu) * rs * w4.x + b4.x;
            float v1 = (bf2f((unsigned short)(pk >> 16)) - mu) * rs * w4.y + b4.y;
            float v2 = (bf2f((unsigned short)(pk >> 32)) - mu) * rs * w4.z + b4.z;
            float v3 = (bf2f((unsigned short)(pk >> 48)) - mu) * rs * w4.w + b4.w;
            *p = pack4(v0, v1, v2, v3);
        }
    }
    __syncthreads();

    // ---- f1 GEMM: xs[64,256] @ f1t -> relu -> outB (global) ----
    const int lr = lane & 15, lk = (lane >> 4) * 8, mr = (lane >> 4) * 4;
    const int wc = wave * 32;
    short8 w0[8], w1[8];
    {
        const unsigned short* wp0 = f1t + (size_t)(wc + lr) * 256 + lk;
        const unsigned short* wp1 = f1t + (size_t)(wc + 16 + lr) * 256 + lk;
        #pragma unroll
        for (int kk = 0; kk < 8; ++kk) {
            w0[kk] = *(const short8*)(wp0 + kk * 32);
            w1[kk] = *(const short8*)(wp1 + kk * 32);
        }
    }
    const float b0 = f1b[wc + lr], b1 = f1b[wc + 16 + lr];
    for (int mt = 0; mt < 4; ++mt) {
        short8 a[8];
        #pragma unroll
        for (int kk = 0; kk < 8; ++kk) a[kk] = afrag256(xs, mt * 16 + lr, kk * 32 + lk);
        f32x4 acc0 = (f32x4){0.f,0.f,0.f,0.f}, acc1 = (f32x4){0.f,0.f,0.f,0.f};
        #pragma unroll
        for (int kk = 0; kk < 8; ++kk) {
            acc0 = __builtin_amdgcn_mfma_f32_16x16x32_bf16(a[kk], w0[kk], acc0, 0, 0, 0);
            acc1 = __builtin_amdgcn_mfma_f32_16x16x32_bf16(a[kk], w1[kk], acc1, 0, 0, 0);
        }
        #pragma unroll
        for (int r = 0; r < 4; ++r) {
            size_t row = (size_t)b * 64 + mt * 16 + mr + r;
            outB[row * 256 + wc + lr]      = f2bf(fmaxf(acc0[r] + b0, 0.f));
            outB[row * 256 + wc + 16 + lr] = f2bf(fmaxf(acc1[r] + b1, 0.f));
        }
    }
}

// ---------------- enc2: f2(relu) + niLN + K + V^T ----------------
__launch_bounds__(512)
__global__ void enc2_kernel(const unsigned short* __restrict__ inB,
                            const unsigned short* __restrict__ f2t, const float* __restrict__ f2b,
                            const float* __restrict__ niw, const float* __restrict__ nib,
                            const unsigned short* __restrict__ kt,  const float* __restrict__ kb,
                            const unsigned short* __restrict__ vwt, const float* __restrict__ vb,
                            unsigned short* __restrict__ ks, unsigned short* __restrict__ vt)
{
    __shared__ unsigned short XL[64 * 256];
    const int b = blockIdx.x, t = threadIdx.x, lane = t & 63, wave = t >> 6;
    const int lr = lane & 15, lk = (lane >> 4) * 8, mr = (lane >> 4) * 4;
    const int wc = wave * 32;

    // stage A <- f1-out batch rows (A-swizzled)
    for (int i = 0; i < 8; ++i) {
        int id = t + 512 * i;
        int row = id >> 6, c4 = (id & 63) * 4;
        *(ull*)(XL + row * 256 + (c4 ^ ((row & 7) << 3))) =
            *(const ull*)(inB + (size_t)b * 16384 + row * 256 + c4);
    }
    __syncthreads();

    // f2 GEMM, hold all accs
    f32x4 acc[4][2];
    {
        short8 w0[8], w1[8];
        const unsigned short* wp0 = f2t + (size_t)(wc + lr) * 256 + lk;
        const unsigned short* wp1 = f2t + (size_t)(wc + 16 + lr) * 256 + lk;
        #pragma unroll
        for (int kk = 0; kk < 8; ++kk) {
            w0[kk] = *(const short8*)(wp0 + kk * 32);
            w1[kk] = *(const short8*)(wp1 + kk * 32);
        }
        #pragma unroll
        for (int mt = 0; mt < 4; ++mt) {
            acc[mt][0] = (f32x4){0.f,0.f,0.f,0.f};
            acc[mt][1] = (f32x4){0.f,0.f,0.f,0.f};
            short8 a[8];
            #pragma unroll
            for (int kk = 0; kk < 8; ++kk) a[kk] = afrag256(XL, mt * 16 + lr, kk * 32 + lk);
            #pragma unroll
            for (int kk = 0; kk < 8; ++kk) {
                acc[mt][0] = __builtin_amdgcn_mfma_f32_16x16x32_bf16(a[kk], w0[kk], acc[mt][0], 0, 0, 0);
                acc[mt][1] = __builtin_amdgcn_mfma_f32_16x16x32_bf16(a[kk], w1[kk], acc[mt][1], 0, 0, 0);
            }
        }
    }
    __syncthreads();       // all A reads done before overwrite
    {
        const float b0 = f2b[wc + lr], b1 = f2b[wc + 16 + lr];
        #pragma unroll
        for (int mt = 0; mt < 4; ++mt)
            #pragma unroll
            for (int r = 0; r < 4; ++r) {
                int lrow = mt * 16 + mr + r;
                XL[lrow * 256 + ((wc + lr)      ^ ((lrow & 7) << 3))] = f2bf(fmaxf(acc[mt][0][r] + b0, 0.f));
                XL[lrow * 256 + ((wc + 16 + lr) ^ ((lrow & 7) << 3))] = f2bf(fmaxf(acc[mt][1][r] + b1, 0.f));
            }
    }
    __syncthreads();

    // ni-LN in place (wave owns rows wave*8..+8)
    {
        const float4 w4 = *(const float4*)(niw + lane * 4);
        const float4 b4 = *(const float4*)(nib + lane * 4);
        for (int rr = 0; rr < 8; ++rr) {
            int row = wave * 8 + rr;
            ull* p = (ull*)(XL + row * 256 + ((lane * 4) ^ ((row & 7) << 3)));
            ull pk = *p;
            float v0 = bf2f((unsigned short)pk),         v1 = bf2f((unsigned short)(pk >> 16));
            float v2 = bf2f((unsigned short)(pk >> 32)), v3 = bf2f((unsigned short)(pk >> 48));
            float s1 = v0 + v1 + v2 + v3;
            float s2 = v0 * v0 + v1 * v1 + v2 * v2 + v3 * v3;
            #pragma unroll
            for (int m = 32; m >= 1; m >>= 1) { s1 += __shfl_xor(s1, m); s2 += __shfl_xor(s2, m); }
            float mu_ = s1 * (1.f / 256.f);
            float rs_ = rsqrtf(s2 * (1.f / 256.f) - mu_ * mu_ + 1e-5f);
            *p = pack4((v0 - mu_) * rs_ * w4.x + b4.x, (v1 - mu_) * rs_ * w4.y + b4.y,
                       (v2 - mu_) * rs_ * w4.z + b4.z, (v3 - mu_) * rs_ * w4.w + b4.w);
        }
    }
    __syncthreads();

    // K GEMM -> ks[b*64+tok][256]
    {
        short8 w0[8], w1[8];
        const unsigned short* wp0 = kt + (size_t)(wc + lr) * 256 + lk;
        const unsigned short* wp1 = kt + (size_t)(wc + 16 + lr) * 256 + lk;
        #pragma unroll
        for (int kk = 0; kk < 8; ++kk) {
            w0[kk] = *(const short8*)(wp0 + kk * 32);
            w1[kk] = *(const short8*)(wp1 + kk * 32);
        }
        const float b0 = kb[wc + lr], b1 = kb[wc + 16 + lr];
        for (int mt = 0; mt < 4; ++mt) {
            short8 a[8];
            #pragma unroll
            for (int kk = 0; kk < 8; ++kk) a[kk] = afrag256(XL, mt * 16 + lr, kk * 32 + lk);
            f32x4 a0 = (f32x4){0.f,0.f,0.f,0.f}, a1 = (f32x4){0.f,0.f,0.f,0.f};
            #pragma unroll
            for (int kk = 0; kk < 8; ++kk) {
                a0 = __builtin_amdgcn_mfma_f32_16x16x32_bf16(a[kk], w0[kk], a0, 0, 0, 0);
                a1 = __builtin_amdgcn_mfma_f32_16x16x32_bf16(a[kk], w1[kk], a1, 0, 0, 0);
            }
            #pragma unroll
            for (int r = 0; r < 4; ++r) {
                size_t row = (size_t)b * 64 + mt * 16 + mr + r;
                ks[row * 256 + wc + lr]      = f2bf(a0[r] + b0);
                ks[row * 256 + wc + 16 + lr] = f2bf(a1[r] + b1);
            }
        }
    }
    // V GEMM -> vt[b][col][tok]
    {
        short8 w0[8], w1[8];
        const unsigned short* wp0 = vwt + (size_t)(wc + lr) * 256 + lk;
        const unsigned short* wp1 = vwt + (size_t)(wc + 16 + lr) * 256 + lk;
        #pragma unroll
        for (int kk = 0; kk < 8; ++kk) {
            w0[kk] = *(const short8*)(wp0 + kk * 32);
            w1[kk] = *(const short8*)(wp1 + kk * 32);
        }
        const float b0 = vb[wc + lr], b1 = vb[wc + 16 + lr];
        for (int mt = 0; mt < 4; ++mt) {
            short8 a[8];
            #pragma unroll
            for (int kk = 0; kk < 8; ++kk) a[kk] = afrag256(XL, mt * 16 + lr, kk * 32 + lk);
            f32x4 a0 = (f32x4){0.f,0.f,0.f,0.f}, a1 = (f32x4){0.f,0.f,0.f,0.f};
            #pragma unroll
            for (int kk = 0; kk < 8; ++kk) {
                a0 = __builtin_amdgcn_mfma_f32_16x16x32_bf16(a[kk], w0[kk], a0, 0, 0, 0);
                a1 = __builtin_amdgcn_mfma_f32_16x16x32_bf16(a[kk], w1[kk], a1, 0, 0, 0);
            }
            int t0 = mt * 16 + mr;
            *(ull*)(vt + (size_t)b * 16384 + (size_t)(wc + lr) * 64 + t0) =
                pack4(a0[0] + b0, a0[1] + b0, a0[2] + b0, a0[3] + b0);
            *(ull*)(vt + (size_t)b * 16384 + (size_t)(wc + 16 + lr) * 64 + t0) =
                pack4(a1[0] + b1, a1[1] + b1, a1[2] + b1, a1[3] + b1);
        }
    }
}

// ---------------- iter: q + attn + GRU + MLP + LN, one launch/iter --------
// block = 4 batches = 32 slot rows. grid 256, 512 threads (8 waves).
__launch_bounds__(512)
__global__ void iter_kernel(
    const unsigned short* __restrict__ Kb, const unsigned short* __restrict__ Vtb,
    const unsigned short* __restrict__ qt,
    const unsigned short* __restrict__ gihb, const unsigned short* __restrict__ ghhb,
    const unsigned short* __restrict__ m1t,  const unsigned short* __restrict__ m2t,
    const float* __restrict__ qb,  const float* __restrict__ bih, const float* __restrict__ bhh,
    const float* __restrict__ pfw, const float* __restrict__ pfb,
    const float* __restrict__ m1b, const float* __restrict__ m2b,
    const float* __restrict__ nsw, const float* __restrict__ nsb,
    float* __restrict__ ping, unsigned short* __restrict__ sraw,
    unsigned short* __restrict__ lnq,
    float* __restrict__ outf, int last)
{
    __shared__ unsigned short SA[32 * 256];      // lnq stage; later pf-LN out
    __shared__ unsigned short SS[32 * 256];      // sraw stage
    __shared__ unsigned short QP[4][16 * 256];   // padded q (rows 8..15 zero)
    __shared__ unsigned short AT[4][16 * 64];    // attn A-operand (padded)
    __shared__ unsigned short US[32 * 256];      // updates; later m1 out (h)
    __shared__ float AF[4][8][72];
    __shared__ float HL[32][256];                // gru out (f32); then slots

    const int t = threadIdx.x, lane = t & 63, wave = t >> 6;
    const int m0 = blockIdx.x * 32;
    const int b0 = blockIdx.x * 4;
    const int lr = lane & 15, lk = (lane >> 4) * 8, mr = (lane >> 4) * 4;
    const int wc = wave * 32;

    // ---- stage SA<-lnq, SS<-sraw; zero QP pad rows + AT ----
    for (int i = 0; i < 4; ++i) {
        int id = t + 512 * i;
        int row = id >> 6, c4 = (id & 63) * 4;
        size_t g = ((size_t)m0 + row) * 256 + c4;
        int sw = c4 ^ ((row & 7) << 3);
        *(ull*)(SA + row * 256 + sw) = *(const ull*)(lnq + g);
        *(ull*)(SS + row * 256 + sw) = *(const ull*)(sraw + g);
    }
    for (int i = t; i < 2048; i += 512) {        // QP rows 8..15 per batch
        int bb = i >> 9, rem = i & 511;
        int row = 8 + (rem >> 6), c4 = (rem & 63) * 4;
        *(ull*)(&QP[bb][row * 256 + c4]) = 0;
    }
    for (int i = t; i < 1024; i += 512) ((ull*)AT)[i] = 0;
    __syncthreads();

    // ---- phase 1: q GEMM (SA @ qt) -> QP ----
    {
        short8 w0[8], w1[8];
        const unsigned short* wp0 = qt + (size_t)(wc + lr) * 256 + lk;
        const unsigned short* wp1 = qt + (size_t)(wc + 16 + lr) * 256 + lk;
        #pragma unroll
        for (int kk = 0; kk < 8; ++kk) {
            w0[kk] = *(const short8*)(wp0 + kk * 32);
            w1[kk] = *(const short8*)(wp1 + kk * 32);
        }
        const float bq0 = qb[wc + lr], bq1 = qb[wc + 16 + lr];
        #pragma unroll
        for (int mt = 0; mt < 2; ++mt) {
            short8 a[8];
            #pragma unroll
            for (int kk = 0; kk < 8; ++kk) a[kk] = afrag256(SA, mt * 16 + lr, kk * 32 + lk);
            f32x4 a0 = (f32x4){0.f,0.f,0.f,0.f}, a1 = (f32x4){0.f,0.f,0.f,0.f};
            #pragma unroll
            for (int kk = 0; kk < 8; ++kk) {
                a0 = __builtin_amdgcn_mfma_f32_16x16x32_bf16(a[kk], w0[kk], a0, 0, 0, 0);
                a1 = __builtin_amdgcn_mfma_f32_16x16x32_bf16(a[kk], w1[kk], a1, 0, 0, 0);
            }
            #pragma unroll
            for (int r = 0; r < 4; ++r) {
                int row = mt * 16 + mr + r;
                int bb = row >> 3, sr = row & 7;
                QP[bb][sr * 256 + ((wc + lr)      ^ (sr << 3))] = f2bf(a0[r] + bq0);
                QP[bb][sr * 256 + ((wc + 16 + lr) ^ (sr << 3))] = f2bf(a1[r] + bq1);
            }
        }
    }
    __syncthreads();

    // ---- phase 2: dots = q @ K^T * scale ----
    {
        const int bb = wave >> 1, th = wave & 1;
        const int b = b0 + bb;
        short8 af[8];
        #pragma unroll
        for (int kk = 0; kk < 8; ++kk) af[kk] = afrag256(QP[bb], lr, kk * 32 + lk);
        #pragma unroll
        for (int tf = 0; tf < 2; ++tf) {
            int n0 = th * 32 + tf * 16;
            f32x4 acc = (f32x4){0.f,0.f,0.f,0.f};
            const unsigned short* kp = Kb + ((size_t)b * 64 + n0 + lr) * 256 + lk;
            #pragma unroll
            for (int kk = 0; kk < 8; ++kk)
                acc = __builtin_amdgcn_mfma_f32_16x16x32_bf16(af[kk], *(const short8*)(kp + kk * 32), acc, 0, 0, 0);
            #pragma unroll
            for (int r = 0; r < 4; ++r)
                if (mr + r < 8) AF[bb][mr + r][n0 + lr] = acc[r] * 0.0625f;
        }
    }
    __syncthreads();

    // ---- phase 3: softmax over slots per token + eps ----
    if (t < 256) {
        int b2 = t >> 6, tok = t & 63;
        float mx = AF[b2][0][tok];
        #pragma unroll
        for (int s = 1; s < 8; ++s) mx = fmaxf(mx, AF[b2][s][tok]);
        float e[8], den = 0.f;
        #pragma unroll
        for (int s = 0; s < 8; ++s) { e[s] = expf(AF[b2][s][tok] - mx); den += e[s]; }
        float inv = 1.f / den;
        #pragma unroll
        for (int s = 0; s < 8; ++s) AF[b2][s][tok] = e[s] * inv + 1e-8f;
    }
    __syncthreads();

    // ---- phase 4: renormalize over tokens -> AT ----
    #pragma unroll
    for (int j = 0; j < 4; ++j) {
        int row = wave * 4 + j;
        int bb = row >> 3, sr = row & 7;
        float v = AF[bb][sr][lane];
        float ssum = v;
        #pragma unroll
        for (int m = 32; m >= 1; m >>= 1) ssum += __shfl_xor(ssum, m);
        AT[bb][sr * 64 + (lane ^ (sr << 3))] = f2bf(v / ssum);
    }
    __syncthreads();

    // ---- phase 5: updates = attn @ V -> US ----
    {
        const int bb = wave >> 1, ch = wave & 1;
        const int b = b0 + bb;
        short8 a0 = afrag64(AT[bb], lr, lk);
        short8 a1 = afrag64(AT[bb], lr, 32 + lk);
        #pragma unroll
        for (int cf = 0; cf < 8; ++cf) {
            int col = ch * 128 + cf * 16 + lr;
            const unsigned short* vp = Vtb + (size_t)b * 16384 + (size_t)col * 64;
            f32x4 acc = (f32x4){0.f,0.f,0.f,0.f};
            acc = __builtin_amdgcn_mfma_f32_16x16x32_bf16(a0, *(const short8*)(vp + lk), acc, 0, 0, 0);
            acc = __builtin_amdgcn_mfma_f32_16x16x32_bf16(a1, *(const short8*)(vp + 32 + lk), acc, 0, 0, 0);
            #pragma unroll
            for (int r = 0; r < 4; ++r)
                if (mr + r < 8) {
                    int row = bb * 8 + mr + r;
                    US[row * 256 + (col ^ ((row & 7) << 3))] = f2bf(acc[r]);
                }
        }
    }
    __syncthreads();

    // ---- phase 6: GRU (verified body) -> HL; then pf-LN -> SA ----
    {
        f32x4 aR[2][2], aZ[2][2], aN[2][2], aH[2][2];
        #pragma unroll
        for (int cf = 0; cf < 2; ++cf)
            #pragma unroll
            for (int m = 0; m < 2; ++m) {
                aR[cf][m] = (f32x4){0.f,0.f,0.f,0.f}; aZ[cf][m] = (f32x4){0.f,0.f,0.f,0.f};
                aN[cf][m] = (f32x4){0.f,0.f,0.f,0.f}; aH[cf][m] = (f32x4){0.f,0.f,0.f,0.f};
            }
        #pragma unroll
        for (int g = 0; g < 3; ++g) {
            #pragma unroll
            for (int cf = 0; cf < 2; ++cf) {
                int col = wc + cf * 16 + lr;
                const unsigned short* px = gihb + (size_t)(g * 256 + col) * 256 + lk;
                const unsigned short* ph = ghhb + (size_t)(g * 256 + col) * 256 + lk;
                short8 wx[8], wh[8];
                #pragma unroll
                for (int kk = 0; kk < 8; ++kk) {
                    wx[kk] = *(const short8*)(px + kk * 32);
                    wh[kk] = *(const short8*)(ph + kk * 32);
                }
                #pragma unroll
                for (int m = 0; m < 2; ++m) {
                    #pragma unroll
                    for (int kk = 0; kk < 8; ++kk) {
                        short8 u = afrag256(US, m * 16 + lr, kk * 32 + lk);
                        short8 s = afrag256(SS, m * 16 + lr, kk * 32 + lk);
                        if (g == 0) {
                            aR[cf][m] = __builtin_amdgcn_mfma_f32_16x16x32_bf16(u, wx[kk], aR[cf][m], 0, 0, 0);
                            aR[cf][m] = __builtin_amdgcn_mfma_f32_16x16x32_bf16(s, wh[kk], aR[cf][m], 0, 0, 0);
                        } else if (g == 1) {
                            aZ[cf][m] = __builtin_amdgcn_mfma_f32_16x16x32_bf16(u, wx[kk], aZ[cf][m], 0, 0, 0);
                            aZ[cf][m] = __builtin_amdgcn_mfma_f32_16x16x32_bf16(s, wh[kk], aZ[cf][m], 0, 0, 0);
                        } else {
                            aN[cf][m] = __builtin_amdgcn_mfma_f32_16x16x32_bf16(u, wx[kk], aN[cf][m], 0, 0, 0);
                            aH[cf][m] = __builtin_amdgcn_mfma_f32_16x16x32_bf16(s, wh[kk], aH[cf][m], 0, 0, 0);
                        }
                    }
                }
            }
        }
        #pragma unroll
        for (int cf = 0; cf < 2; ++cf) {
            int col = wc + cf * 16 + lr;
            float bR  = bih[col] + bhh[col];
            float bZ  = bih[col + 256] + bhh[col + 256];
            float bXN = bih[col + 512], bHN = bhh[col + 512];
            #pragma unroll
            for (int m = 0; m < 2; ++m)
                #pragma unroll
                for (int r = 0; r < 4; ++r) {
                    int row = m * 16 + mr + r;
                    float prev = ping[((size_t)m0 + row) * 256 + col];
                    float rr = sigmoidf_(aR[cf][m][r] + bR);
                    float zz = sigmoidf_(aZ[cf][m][r] + bZ);
                    float nn = tanhf(aN[cf][m][r] + bXN + rr * (aH[cf][m][r] + bHN));
                    HL[row][col] = (1.f - zz) * nn + zz * prev;
                }
        }
    }
    __syncthreads();
    // pf-LN: HL -> SA (bf16 A-layout), LDS only
    {
        const float4 w4 = *(const float4*)(pfw + lane * 4);
        const float4 b4 = *(const float4*)(pfb + lane * 4);
        #pragma unroll
        for (int rr = 0; rr < 4; ++rr) {
            int row = wave * 4 + rr;
            float4 v = *(const float4*)&HL[row][lane * 4];
            float s1 = v.x + v.y + v.z + v.w;
            float s2 = v.x * v.x + v.y * v.y + v.z * v.z + v.w * v.w;
            #pragma unroll
            for (int m = 32; m >= 1; m >>= 1) { s1 += __shfl_xor(s1, m); s2 += __shfl_xor(s2, m); }
            float mu_ = s1 * (1.f / 256.f);
            float rs_ = rsqrtf(s2 * (1.f / 256.f) - mu_ * mu_ + 1e-5f);
            *(ull*)(SA + row * 256 + ((lane * 4) ^ ((row & 7) << 3))) = pack4(
                (v.x - mu_) * rs_ * w4.x + b4.x, (v.y - mu_) * rs_ * w4.y + b4.y,
                (v.z - mu_) * rs_ * w4.z + b4.z, (v.w - mu_) * rs_ * w4.w + b4.w);
        }
    }
    __syncthreads();

    // ---- phase 7: m1 (relu) : SA @ m1t -> US ----
    {
        short8 w0[8], w1[8];
        const unsigned short* wp0 = m1t + (size_t)(wc + lr) * 256 + lk;
        const unsigned short* wp1 = m1t + (size_t)(wc + 16 + lr) * 256 + lk;
        #pragma unroll
        for (int kk = 0; kk < 8; ++kk) {
            w0[kk] = *(const short8*)(wp0 + kk * 32);
            w1[kk] = *(const short8*)(wp1 + kk * 32);
        }
        const float b0 = m1b[wc + lr], b1 = m1b[wc + 16 + lr];
        #pragma unroll
        for (int mt = 0; mt < 2; ++mt) {
            short8 a[8];
            #pragma unroll
            for (int kk = 0; kk < 8; ++kk) a[kk] = afrag256(SA, mt * 16 + lr, kk * 32 + lk);
            f32x4 a0 = (f32x4){0.f,0.f,0.f,0.f}, a1 = (f32x4){0.f,0.f,0.f,0.f};
            #pragma unroll
            for (int kk = 0; kk < 8; ++kk) {
                a0 = __builtin_amdgcn_mfma_f32_16x16x32_bf16(a[kk], w0[kk], a0, 0, 0, 0);
                a1 = __builtin_amdgcn_mfma_f32_16x16x32_bf16(a[kk], w1[kk], a1, 0, 0, 0);
            }
            #pragma unroll
            for (int r = 0; r < 4; ++r) {
                int row = mt * 16 + mr + r;
                US[row * 256 + ((wc + lr)      ^ ((row & 7) << 3))] = f2bf(fmaxf(a0[r] + b0, 0.f));
                US[row * 256 + ((wc + 16 + lr) ^ ((row & 7) << 3))] = f2bf(fmaxf(a1[r] + b1, 0.f));
            }
        }
    }
    __syncthreads();

    // ---- phase 8: m2 + residual -> HL; final LN + state/out writes ----
    {
        short8 w0[8], w1[8];
        const unsigned short* wp0 = m2t + (size_t)(wc + lr) * 256 + lk;
        const unsigned short* wp1 = m2t + (size_t)(wc + 16 + lr) * 256 + lk;
        #pragma unroll
        for (int kk = 0; kk < 8; ++kk) {
            w0[kk] = *(const short8*)(wp0 + kk * 32);
            w1[kk] = *(const short8*)(wp1 + kk * 32);
        }
        const float b0 = m2b[wc + lr], b1 = m2b[wc + 16 + lr];
        #pragma unroll
        for (int mt = 0; mt < 2; ++mt) {
            short8 a[8];
            #pragma unroll
            for (int kk = 0; kk < 8; ++kk) a[kk] = afrag256(US, mt * 16 + lr, kk * 32 + lk);
            f32x4 a0 = (f32x4){0.f,0.f,0.f,0.f}, a1 = (f32x4){0.f,0.f,0.f,0.f};
            #pragma unroll
            for (int kk = 0; kk < 8; ++kk) {
                a0 = __builtin_amdgcn_mfma_f32_16x16x32_bf16(a[kk], w0[kk], a0, 0, 0, 0);
                a1 = __builtin_amdgcn_mfma_f32_16x16x32_bf16(a[kk], w1[kk], a1, 0, 0, 0);
            }
            #pragma unroll
            for (int r = 0; r < 4; ++r) {
                int row = mt * 16 + mr + r;
                HL[row][wc + lr]      = a0[r] + b0 + HL[row][wc + lr];
                HL[row][wc + 16 + lr] = a1[r] + b1 + HL[row][wc + 16 + lr];
            }
        }
    }
    __syncthreads();
    {
        const float4 w4 = *(const float4*)(nsw + lane * 4);
        const float4 b4 = *(const float4*)(nsb + lane * 4);
        #pragma unroll
        for (int rr = 0; rr < 4; ++rr) {
            int row = wave * 4 + rr;
            size_t off = ((size_t)m0 + row) * 256 + lane * 4;
            float4 v = *(const float4*)&HL[row][lane * 4];
            if (last) {
                *(float4*)(outf + off) = v;
            } else {
                float s1 = v.x + v.y + v.z + v.w;
                float s2 = v.x * v.x + v.y * v.y + v.z * v.z + v.w * v.w;
                #pragma unroll
                for (int m = 32; m >= 1; m >>= 1) { s1 += __shfl_xor(s1, m); s2 += __shfl_xor(s2, m); }
                float mu_ = s1 * (1.f / 256.f);
                float rs_ = rsqrtf(s2 * (1.f / 256.f) - mu_ * mu_ + 1e-5f);
                *(float4*)(ping + off) = v;
                *(ull*)(sraw + off) = pack4(v.x, v.y, v.z, v.w);
                *(ull*)(lnq + off) = pack4(
                    (v.x - mu_) * rs_ * w4.x + b4.x, (v.y - mu_) * rs_ * w4.y + b4.y,
                    (v.z - mu_) * rs_ * w4.z + b4.z, (v.w - mu_) * rs_ * w4.w + b4.w);
            }
        }
    }
}

// ------------------------------------------------------------------
extern "C" void kernel_launch(void* const* d_in, const int* in_sizes, int n_in,
                              void* d_out, int out_size, void* d_ws, size_t ws_size,
                              hipStream_t stream) {
    (void)in_sizes; (void)n_in; (void)ws_size; (void)out_size;
    unsigned short* wsb  = (unsigned short*)d_ws;
    unsigned short* bufB = wsb + (1u << 20);         // f1 out (33 MB)
    unsigned short* ksb  = bufB + 16777216;          // K
    unsigned short* vtb  = ksb + 16777216;           // V^T
    float* ping = (float*)(vtb + 16777216);
    unsigned short* srawb = (unsigned short*)(ping + 2097152);
    unsigned short* lnqb  = srawb + 2097152;

    const unsigned short* f1t  = wsb;
    const unsigned short* f2t  = wsb + 65536;
    const unsigned short* kt   = wsb + 131072;
    const unsigned short* vwt  = wsb + 196608;
    const unsigned short* qt   = wsb + 262144;
    const unsigned short* m1t  = wsb + 327680;
    const unsigned short* m2t  = wsb + 393216;
    const unsigned short* gihb = wsb + 458752;
    const unsigned short* ghhb = wsb + 655360;

    convert_weights<<<dim3(1664), dim3(512), 0, stream>>>(
        (const float*)d_in[6],  (const float*)d_in[8],  (const float*)d_in[14],
        (const float*)d_in[16], (const float*)d_in[12], (const float*)d_in[26],
        (const float*)d_in[28], (const float*)d_in[18], (const float*)d_in[19], wsb);

    enc1_kernel<<<dim3(1024), dim3(512), 0, stream>>>(
        (const float*)d_in[0], (const float*)d_in[2], (const float*)d_in[3],
        (const float*)d_in[4], (const float*)d_in[5],
        f1t, (const float*)d_in[7], bufB);

    enc2_kernel<<<dim3(1024), dim3(512), 0, stream>>>(
        bufB, f2t, (const float*)d_in[9],
        (const float*)d_in[10], (const float*)d_in[11],
        kt, (const float*)d_in[15], vwt, (const float*)d_in[17],
        ksb, vtb);

    slot_init<<<dim3(1024), dim3(512), 0, stream>>>(
        (const float*)d_in[30], (const float*)d_in[31], (const float*)d_in[1],
        (const float*)d_in[22], (const float*)d_in[23], ping, srawb, lnqb);

    for (int it = 0; it < 5; ++it) {
        iter_kernel<<<dim3(256), dim3(512), 0, stream>>>(
            ksb, vtb, qt, gihb, ghhb, m1t, m2t,
            (const float*)d_in[13], (const float*)d_in[20], (const float*)d_in[21],
            (const float*)d_in[24], (const float*)d_in[25],
            (const float*)d_in[27], (const float*)d_in[29],
            (const float*)d_in[22], (const float*)d_in[23],
            ping, srawb, lnqb,
            (float*)d_out, it == 4 ? 1 : 0);
    }
}